// Round 18
// baseline (1584.683 us; speedup 1.0000x reference)
//
#include <hip/hip_runtime.h>
#include <hip/hip_bf16.h>

// ---------- types / constants ----------
typedef short bf16x8 __attribute__((ext_vector_type(8)));
typedef float f32x4 __attribute__((ext_vector_type(4)));
typedef unsigned int u32x4 __attribute__((ext_vector_type(4)));

#define B_   16
#define LSEQ 4096
#define DM   512
#define NST  32
#define NL   4
#define NCH  16
#define TC   256
#define RF   256            // full r count (r = b*16 + c)
#define KREVN 544
#define SZC  (NL*NST*DM)

__device__ __forceinline__ unsigned short f2us(float f){
  unsigned int x = __float_as_uint(f);
  x += 0x7fff + ((x >> 16) & 1);
  return (unsigned short)(x >> 16);
}
__device__ __forceinline__ float us2f(unsigned short u){
  return __uint_as_float(((unsigned int)u) << 16);
}

// ---------- K0: per-layer SSM coefficient planes (fp32) ----------
__global__ void k_coef(const float* log_dt, const float* C_re,
                       const float* C_im, const float* lAr,
                       const float* Aimg, float* coef){
  int tid = blockIdx.x * 256 + threadIdx.x;
  if (tid >= NL*NST*DM) return;
  int h  = tid & (DM-1);
  int n  = (tid >> 9) & (NST-1);
  int ly = tid >> 14;
  int ihn = (ly*DM + h)*NST + n;
  float dt  = expf(log_dt[ly*DM + h]);
  float Are = -expf(lAr[ihn]);
  float Aim = Aimg[ihn];
  float dar = dt*Are, dai = dt*Aim;
  float er  = expf(dar);
  float wre = er*cosf(dai), wim = er*sinf(dai);
  float Cr  = C_re[ihn], Ci = C_im[ihn];
  float e1r = wre - 1.0f, e1i = wim;
  float tr = Cr*e1r - Ci*e1i;
  float ti = Cr*e1i + Ci*e1r;
  float inv = 1.0f/(Are*Are + Aim*Aim);
  float ccr = (tr*Are + ti*Aim)*inv;
  float cci = (ti*Are - tr*Aim)*inv;
  float eT = expf(dar*(float)TC);
  float aT = dai*(float)TC;
  coef[0*SZC + tid] = wre;
  coef[1*SZC + tid] = wim;
  coef[2*SZC + tid] = 2.0f*ccr;
  coef[3*SZC + tid] = -2.0f*cci;
  coef[4*SZC + tid] = eT*cosf(aT);
  coef[5*SZC + tid] = eT*sinf(aT);
}

// ---------- Wconv fp32 -> bf16 ----------
__global__ void k_cvt(const float* Wc, unsigned short* Wcb){
  int tid = blockIdx.x * 256 + threadIdx.x;
  const float4 a = *(const float4*)(Wc + (size_t)tid*8);
  const float4 b = *(const float4*)(Wc + (size_t)tid*8 + 4);
  ushort4 r0, r1;
  r0.x = f2us(a.x); r0.y = f2us(a.y); r0.z = f2us(a.z); r0.w = f2us(a.w);
  r1.x = f2us(b.x); r1.y = f2us(b.y); r1.z = f2us(b.z); r1.w = f2us(b.w);
  *(ushort4*)(Wcb + (size_t)tid*8)     = r0;
  *(ushort4*)(Wcb + (size_t)tid*8 + 4) = r1;
}

// ---------- pz = z @ Wp^T + bp ----------
__global__ void k_proj(const float* z, const float* Wp, const float* bp, float* pz){
  int tid = blockIdx.x * 256 + threadIdx.x;
  if (tid >= B_*DM) return;
  int d = tid & (DM-1), b = tid >> 9;
  float acc = bp[d];
  const float* zr = z  + b*256;
  const float* wr = Wp + d*256;
  for (int k = 0; k < 256; ++k) acc = fmaf(zr[k], wr[k], acc);
  pz[tid] = acc;
}

// ---------- fused broadcast + transpose: x[m][h] = pz+pos (bf16) AND xT[h][r][j] ----------
__global__ __launch_bounds__(256) void k_bcastT(const float* pz, const float* pos,
                                                unsigned short* x, unsigned short* xT){
  __shared__ unsigned short t[64*512];
  int blk = blockIdx.x;                 // 1024 blocks
  int rr = blk >> 2;
  int j0 = (blk & 3) << 6;
  int tt = threadIdx.x;
  int lane = tt & 63, wv = tt >> 6;
  int b = (blk * 64) >> 12;             // batch, constant within block
  float4 p0 = *(const float4*)(pz + b*DM + lane*8);
  float4 p1 = *(const float4*)(pz + b*DM + lane*8 + 4);
  for (int rw = 0; rw < 16; ++rw){
    int jl = wv*16 + rw;
    size_t m = (size_t)blk*64 + jl;
    int l = (int)(m & 4095);
    const float* pe = pos + (size_t)l*DM + lane*8;
    float4 e0 = *(const float4*)pe;
    float4 e1 = *(const float4*)(pe + 4);
    ushort4 o0, o1;
    o0.x = f2us(p0.x+e0.x); o0.y = f2us(p0.y+e0.y); o0.z = f2us(p0.z+e0.z); o0.w = f2us(p0.w+e0.w);
    o1.x = f2us(p1.x+e1.x); o1.y = f2us(p1.y+e1.y); o1.z = f2us(p1.z+e1.z); o1.w = f2us(p1.w+e1.w);
    unsigned short* xr = x + m*DM + lane*8;
    *(ushort4*)xr       = o0;
    *(ushort4*)(xr + 4) = o1;
    int slot = lane ^ ((jl >> 3) & 7);
    *(ushort4*)&t[jl*512 + slot*8]     = o0;
    *(ushort4*)&t[jl*512 + slot*8 + 4] = o1;
  }
  __syncthreads();
  #pragma unroll
  for (int p = 0; p < 16; ++p){
    int s = p*256 + tt;
    int h = s >> 3;
    int jg = (s & 7) << 3;
    int gh = h >> 3, h0 = h & 7;
    int slot = gh ^ (jg >> 3);
    unsigned int e0 = t[(jg+0)*512 + slot*8 + h0];
    unsigned int e1 = t[(jg+1)*512 + slot*8 + h0];
    unsigned int e2 = t[(jg+2)*512 + slot*8 + h0];
    unsigned int e3 = t[(jg+3)*512 + slot*8 + h0];
    unsigned int e4 = t[(jg+4)*512 + slot*8 + h0];
    unsigned int e5 = t[(jg+5)*512 + slot*8 + h0];
    unsigned int e6 = t[(jg+6)*512 + slot*8 + h0];
    unsigned int e7 = t[(jg+7)*512 + slot*8 + h0];
    u32x4 d;
    d.x = e0 | (e1 << 16);
    d.y = e2 | (e3 << 16);
    d.z = e4 | (e5 << 16);
    d.w = e6 | (e7 << 16);
    *(u32x4*)(xT + ((size_t)h*RF + rr)*256 + j0 + jg) = d;
  }
}

// ---------- zero Krev buffers (both, contiguous; once) ----------
__global__ void k_kz(u32x4* p){
  p[blockIdx.x*256 + threadIdx.x] = (u32x4){0,0,0,0};
}

// ---------- Krev + V generation for layer ly ----------
__global__ void k_kv(const float* log_dt, const float* lAr, const float* Aimg,
                     const float* coef, unsigned short* KrevA, unsigned short* KrevB,
                     unsigned short* V, int ly){
  int tid = blockIdx.x*256 + threadIdx.x;
  int h   = tid >> 9;
  int tau = tid & 511;
  if (tau > 256) return;
  float taf = (float)tau;
  int hb = ly*DM + h;
  float dt = expf(log_dt[hb]);
  float kacc = 0.f;
  unsigned int vre[16], vim[16];
  #pragma unroll
  for (int n = 0; n < 32; n += 2){
    float vr[2], vi[2];
    #pragma unroll
    for (int s = 0; s < 2; ++s){
      int nn = n + s;
      int ihn = hb*NST + nn;
      float dar = -dt*expf(lAr[ihn]);
      float dai =  dt*Aimg[ihn];
      int o = ((ly*NST + nn) << 9) + h;
      float c2r = coef[2*SZC + o], c2i = coef[3*SZC + o];
      float er = expf(dar*taf);
      float Wr = er*cosf(dai*taf), Wi = er*sinf(dai*taf);
      float a = c2r*Wr + c2i*Wi;
      kacc += a;
      vr[s] = a;
      vi[s] = c2i*Wr - c2r*Wi;
    }
    vre[n>>1] = (unsigned int)f2us(vr[0]) | ((unsigned int)f2us(vr[1]) << 16);
    vim[n>>1] = (unsigned int)f2us(vi[0]) | ((unsigned int)f2us(vi[1]) << 16);
  }
  if (tau <= 255){
    KrevA[(size_t)h*KREVN + 255 - tau] = f2us(kacc);
    if (tau < 255) KrevB[(size_t)h*KREVN + 254 - tau] = f2us(kacc);
  }
  if (tau >= 1){
    unsigned short* vp = V + ((size_t)h*256 + (tau-1))*64;
    u32x4* vp4 = (u32x4*)vp;
    vp4[0] = (u32x4){vre[0],vre[1],vre[2],vre[3]};
    vp4[1] = (u32x4){vre[4],vre[5],vre[6],vre[7]};
    vp4[2] = (u32x4){vre[8],vre[9],vre[10],vre[11]};
    vp4[3] = (u32x4){vre[12],vre[13],vre[14],vre[15]};
    vp4[4] = (u32x4){vim[0],vim[1],vim[2],vim[3]};
    vp4[5] = (u32x4){vim[4],vim[5],vim[6],vim[7]};
    vp4[6] = (u32x4){vim[8],vim[9],vim[10],vim[11]};
    vp4[7] = (u32x4){vim[12],vim[13],vim[14],vim[15]};
  }
}

// ---------- Wv generation ----------
__global__ void k_wv(const float* coef, unsigned short* Wv, int ly){
  int tid = blockIdx.x*64 + threadIdx.x;
  int n = tid & 31, h = (tid >> 5) & 511;
  int o = ((ly*NST + n) << 9) + h;
  float wre = coef[0*SZC + o], wim = coef[1*SZC + o];
  float cr = 1.f, ci = 0.f;
  unsigned short* pr = Wv + ((size_t)h*64 + n)*256;
  unsigned short* pi = pr + (size_t)32*256;
  for (int blk = 0; blk < 16; ++blk){
    unsigned int pr_[8] = {0,0,0,0,0,0,0,0};
    unsigned int pi_[8] = {0,0,0,0,0,0,0,0};
    #pragma unroll
    for (int i = 0; i < 16; ++i){
      int pos = 15 - i;
      pr_[pos>>1] |= (unsigned int)f2us(cr) << ((pos&1)*16);
      pi_[pos>>1] |= (unsigned int)f2us(ci) << ((pos&1)*16);
      float nr = cr*wre - ci*wim;
      ci = cr*wim + ci*wre;
      cr = nr;
    }
    int jb = 240 - blk*16;
    *(u32x4*)(pr + jb)     = (u32x4){pr_[0],pr_[1],pr_[2],pr_[3]};
    *(u32x4*)(pr + jb + 8) = (u32x4){pr_[4],pr_[5],pr_[6],pr_[7]};
    *(u32x4*)(pi + jb)     = (u32x4){pi_[0],pi_[1],pi_[2],pi_[3]};
    *(u32x4*)(pi + jb + 8) = (u32x4){pi_[4],pi_[5],pi_[6],pi_[7]};
  }
}

// ---------- transpose yT[h][r][l] -> ybuf[m][h] (bf16, full) ----------
__global__ void k_yT(const unsigned short* yT, unsigned short* ybuf){
  __shared__ unsigned short t[64][72];
  int blk = blockIdx.x;
  int h0 = (blk & 7) << 6;
  int l0 = ((blk >> 3) & 3) << 6;
  int rg = blk >> 5;                     // 0..255
  int tt = threadIdx.x;
  #pragma unroll
  for (int p = 0; p < 2; ++p){
    int e = p*2048 + tt*8;
    int row = e >> 6, col = e & 63;
    *(uint4*)&t[row][col] = *(const uint4*)(yT + ((size_t)(h0+row)*RF + rg)*256 + l0 + col);
  }
  __syncthreads();
  #pragma unroll
  for (int p = 0; p < 2; ++p){
    int e = p*2048 + tt*8;
    int orow = e >> 6, oc = e & 63;
    unsigned int d0 = (unsigned int)t[oc+0][orow] | ((unsigned int)t[oc+1][orow] << 16);
    unsigned int d1 = (unsigned int)t[oc+2][orow] | ((unsigned int)t[oc+3][orow] << 16);
    unsigned int d2 = (unsigned int)t[oc+4][orow] | ((unsigned int)t[oc+5][orow] << 16);
    unsigned int d3 = (unsigned int)t[oc+6][orow] | ((unsigned int)t[oc+7][orow] << 16);
    *(u32x4*)(ybuf + ((size_t)(rg*256 + l0 + orow))*DM + h0 + oc) = (u32x4){d0,d1,d2,d3};
  }
}

// ---------- pass2: fused local-state GEMM + in-block scan + Toeplitz/state GEMM ----------
__global__ __launch_bounds__(256) void k_p2(const unsigned short* xT, const unsigned short* KrevA,
      const unsigned short* KrevB, const unsigned short* V, const unsigned short* Wv,
      const float* coef, const float* Dsk, unsigned short* yT, int ly){
  __shared__ unsigned short us[64*256];
  __shared__ unsigned short st[64*64];
  int blk = blockIdx.x;
  int h  = blk >> 2;
  int r0 = (blk & 3) << 6;
  int tt = threadIdx.x;
  int lane = tt & 63, wv = tt >> 6;
  int la = lane & 15, kb = lane >> 4;
  const unsigned short* xp = xT + ((size_t)h*RF + r0)*256;
  #pragma unroll
  for (int p = 0; p < 8; ++p){
    int e = (p*256 + tt)*8;
    int r = e >> 8, j = e & 255;
    int g = ((j >> 3) ^ (r & 7));
    *(uint4*)&us[r*256 + g*8] = *(const uint4*)(xp + r*256 + j);
  }
  __syncthreads();
  // local states: S[rl][m2] = sum_j u[rl][j] * Wv[m2][j]
  {
    int wr = wv & 1, wm = wv >> 1;
    f32x4 sacc[2][2] = {};
    const unsigned short* wvp = Wv + (size_t)h*64*256;
    for (int j0 = 0; j0 < 256; j0 += 32){
      bf16x8 uf[2], wf[2];
      #pragma unroll
      for (int i = 0; i < 2; ++i){
        int r = wr*32 + i*16 + la;
        int g = (((j0 + kb*8) >> 3) ^ (r & 7));
        uf[i] = *(const bf16x8*)&us[r*256 + g*8];
      }
      #pragma unroll
      for (int i = 0; i < 2; ++i){
        int m2 = wm*32 + i*16 + la;
        wf[i] = *(const bf16x8*)(wvp + m2*256 + j0 + kb*8);
      }
      #pragma unroll
      for (int a = 0; a < 2; ++a)
        #pragma unroll
        for (int b = 0; b < 2; ++b)
          sacc[a][b] = __builtin_amdgcn_mfma_f32_16x16x32_bf16(uf[a], wf[b], sacc[a][b], 0, 0, 0);
    }
    #pragma unroll
    for (int a = 0; a < 2; ++a)
      #pragma unroll
      for (int b = 0; b < 2; ++b)
        #pragma unroll
        for (int q = 0; q < 4; ++q){
          int rl = wr*32 + a*16 + kb*4 + q;
          int m2 = wm*32 + b*16 + la;
          int slot = ((m2 >> 3) ^ (rl & 7));
          st[rl*64 + slot*8 + (m2 & 7)] = f2us(sacc[a][b][q]);
        }
  }
  __syncthreads();
  // in-block scan
  {
    int nm = lane & 31;
    float sgn = (lane < 32) ? -1.f : 1.f;
    int o = ((ly*NST + nm) << 9) + h;
    float wTre = coef[4*SZC + o], wTim = coef[5*SZC + o];
    float S = 0.f;
    int slot0 = lane >> 3, c0 = lane & 7;
    for (int c = 0; c < NCH; ++c){
      int rl = wv*16 + c;
      int idx = rl*64 + ((slot0 ^ (rl & 7)) << 3) + c0;
      float loc = us2f(st[idx]);
      st[idx] = f2us(S);
      float prt = __shfl_xor(S, 32);
      S = fmaf(wTre, S, fmaf(sgn*wTim, prt, loc));
    }
  }
  __syncthreads();
  int wl = wv >> 1, wr = wv & 1;
  const unsigned short* KA = KrevA + (size_t)h*KREVN;
  const unsigned short* KB = KrevB + (size_t)h*KREVN;
  const unsigned short* Vp = V + (size_t)h*256*64;
  float Dv = Dsk[ly*DM + h];
  unsigned short* yp = yT + (size_t)h*RF*256;
  for (int lt = 0; lt < 4; ++lt){
    int l0w = lt*64 + wl*32;
    f32x4 acc[2][2] = {};
    int jsteps = (l0w >> 5) + 1;
    for (int js = 0; js < jsteps; ++js){
      int j0 = js*32;
      bf16x8 uf[2], tf[2];
      #pragma unroll
      for (int i = 0; i < 2; ++i){
        int rb = wr*32 + i*16 + la;
        int g = (((j0 + kb*8) >> 3) ^ (rb & 7));
        uf[i] = *(const bf16x8*)&us[rb*256 + g*8];
      }
      #pragma unroll
      for (int i = 0; i < 2; ++i){
        int l = l0w + i*16 + la;
        int idx = 255 - l + j0 + kb*8;
        const unsigned short* base = (idx & 1) ? (KB + idx - 1) : (KA + idx);
        unsigned int d0 = *(const unsigned int*)(base);
        unsigned int d1 = *(const unsigned int*)(base + 2);
        unsigned int d2 = *(const unsigned int*)(base + 4);
        unsigned int d3 = *(const unsigned int*)(base + 6);
        tf[i] = __builtin_bit_cast(bf16x8, (u32x4){d0,d1,d2,d3});
      }
      #pragma unroll
      for (int a = 0; a < 2; ++a)
        #pragma unroll
        for (int b = 0; b < 2; ++b)
          acc[a][b] = __builtin_amdgcn_mfma_f32_16x16x32_bf16(uf[a], tf[b], acc[a][b], 0, 0, 0);
    }
    #pragma unroll
    for (int ms = 0; ms < 2; ++ms){
      int m0 = ms*32;
      bf16x8 sf[2], vf[2];
      #pragma unroll
      for (int i = 0; i < 2; ++i){
        int rb = wr*32 + i*16 + la;
        int slot = ((m0 + kb*8) >> 3) ^ (rb & 7);
        sf[i] = *(const bf16x8*)&st[rb*64 + slot*8];
      }
      #pragma unroll
      for (int i = 0; i < 2; ++i){
        int l = l0w + i*16 + la;
        vf[i] = *(const bf16x8*)(Vp + l*64 + m0 + kb*8);
      }
      #pragma unroll
      for (int a = 0; a < 2; ++a)
        #pragma unroll
        for (int b = 0; b < 2; ++b)
          acc[a][b] = __builtin_amdgcn_mfma_f32_16x16x32_bf16(sf[a], vf[b], acc[a][b], 0, 0, 0);
    }
    #pragma unroll
    for (int a = 0; a < 2; ++a)
      #pragma unroll
      for (int b = 0; b < 2; ++b)
        #pragma unroll
        for (int q = 0; q < 4; ++q){
          int rb = wr*32 + a*16 + kb*4 + q;
          int l  = l0w + b*16 + la;
          int g = ((l >> 3) ^ (rb & 7));
          float u = us2f(us[rb*256 + g*8 + (l & 7)]);
          float y = acc[a][b][q] + Dv*u;
          float gl = 0.5f*y*(1.0f + erff(y*0.70710678118654752f));
          yp[(r0 + rb)*256 + l] = f2us(gl);
        }
  }
}

// ---------- GLU GEMM: A staged in LDS; B operands DIRECT from global (L2-resident) ----------
__global__ __launch_bounds__(256,2) void k_gemm(const unsigned short* A, const unsigned short* Bw,
                                                const float* bias, unsigned short* x, int ly){
  __shared__ short As[128*64];
  const int K = 512;
  int bid = blockIdx.x;
  int swz = (bid & 7) * 256 + (bid >> 3);     // XCD-aware bijective swizzle (2048 = 8*256)
  int Mt = swz >> 2;
  int Nt = swz & 3;
  int lane = threadIdx.x & 63, wv = threadIdx.x >> 6;
  int wm = wv >> 1, wn = wv & 1;
  f32x4 acc[2][4][4] = {};
  const unsigned short* Ag = A  + (size_t)Mt * 128 * K;
  const unsigned short* B0 = Bw + (size_t)ly * 1024 * K + (size_t)Nt * 128 * K;
  const unsigned short* B1 = B0 + (size_t)512 * K;
  for (int k0 = 0; k0 < K; k0 += 64){
    __syncthreads();
    #pragma unroll
    for (int p = 0; p < 4; ++p){
      int e = (p*256 + threadIdx.x) * 8;
      int row = e >> 6, k = e & 63;
      int sw = ((k >> 3) ^ (row & 7)) << 3;
      *(uint4*)(&As[row*64 + sw]) = *(const uint4*)(Ag + (size_t)row*K + k0 + k);
    }
    __syncthreads();
    #pragma unroll
    for (int kk = 0; kk < 64; kk += 32){
      int kb = (kk >> 3) + (lane >> 4);
      bf16x8 af[4], b0[4], b1[4];
      #pragma unroll
      for (int i = 0; i < 4; ++i){
        int ra = wm*64 + i*16 + (lane & 15);
        af[i] = *(const bf16x8*)(&As[ra*64 + ((kb ^ (ra & 7)) << 3)]);
        int rb = wn*64 + i*16 + (lane & 15);
        // direct from L2: identical bf16x8 to what the old LDS round-trip produced
        b0[i] = *(const bf16x8*)(B0 + (size_t)rb*K + k0 + kb*8);
        b1[i] = *(const bf16x8*)(B1 + (size_t)rb*K + k0 + kb*8);
      }
      #pragma unroll
      for (int i = 0; i < 4; ++i)
        #pragma unroll
        for (int j = 0; j < 4; ++j){
          acc[0][i][j] = __builtin_amdgcn_mfma_f32_16x16x32_bf16(af[i], b0[j], acc[0][i][j], 0, 0, 0);
          acc[1][i][j] = __builtin_amdgcn_mfma_f32_16x16x32_bf16(af[i], b1[j], acc[1][i][j], 0, 0, 0);
        }
    }
  }
  #pragma unroll
  for (int j = 0; j < 4; ++j){
    int n = Nt*128 + wn*64 + j*16 + (lane & 15);
    float ba = bias[ly*1024 + n];
    float bg = bias[ly*1024 + 512 + n];
    #pragma unroll
    for (int i = 0; i < 4; ++i){
      int mb = Mt*128 + wm*64 + i*16 + ((lane >> 4) << 2);
      #pragma unroll
      for (int q = 0; q < 4; ++q){
        float a = acc[0][i][j][q] + ba;
        float g = acc[1][i][j][q] + bg;
        float glu = a / (1.0f + expf(-g));
        size_t off = (size_t)(mb + q) * DM + n;
        x[off] = f2us(us2f(x[off]) + glu);
      }
    }
  }
}

// ---------- fused LayerNorm + transpose (layers 0..NL-2) ----------
__global__ __launch_bounds__(256) void k_lnxT(unsigned short* x, const float* gam,
                                              const float* bet, unsigned short* xT, int ly){
  __shared__ unsigned short t[64*512];
  int blk = blockIdx.x;                 // 1024 blocks
  int rr = blk >> 2;
  int j0 = (blk & 3) << 6;
  int tt = threadIdx.x;
  int lane = tt & 63, wv = tt >> 6;
  const float* gp  = gam + ly*DM + lane*8;
  const float* bp2 = bet + ly*DM + lane*8;
  float4 g0 = *(const float4*)gp,  g1 = *(const float4*)(gp + 4);
  float4 b0 = *(const float4*)bp2, b1 = *(const float4*)(bp2 + 4);
  for (int rw = 0; rw < 16; ++rw){
    int jl = wv*16 + rw;
    size_t m = (size_t)blk*64 + jl;
    unsigned short* xr = x + m*DM + lane*8;
    ushort4 a0 = *(const ushort4*)xr;
    ushort4 a1 = *(const ushort4*)(xr + 4);
    float v[8];
    v[0]=us2f(a0.x); v[1]=us2f(a0.y); v[2]=us2f(a0.z); v[3]=us2f(a0.w);
    v[4]=us2f(a1.x); v[5]=us2f(a1.y); v[6]=us2f(a1.z); v[7]=us2f(a1.w);
    float s = 0.f, s2 = 0.f;
    #pragma unroll
    for (int i = 0; i < 8; ++i){ s += v[i]; s2 += v[i]*v[i]; }
    #pragma unroll
    for (int mm = 32; mm > 0; mm >>= 1){
      s  += __shfl_xor(s,  mm, 64);
      s2 += __shfl_xor(s2, mm, 64);
    }
    float mu  = s * (1.0f/DM);
    float var = s2 * (1.0f/DM) - mu*mu;
    float rs  = rsqrtf(var + 1e-5f);
    ushort4 o0, o1;
    o0.x = f2us((v[0]-mu)*rs*g0.x + b0.x);
    o0.y = f2us((v[1]-mu)*rs*g0.y + b0.y);
    o0.z = f2us((v[2]-mu)*rs*g0.z + b0.z);
    o0.w = f2us((v[3]-mu)*rs*g0.w + b0.w);
    o1.x = f2us((v[4]-mu)*rs*g1.x + b1.x);
    o1.y = f2us((v[5]-mu)*rs*g1.y + b1.y);
    o1.z = f2us((v[6]-mu)*rs*g1.z + b1.z);
    o1.w = f2us((v[7]-mu)*rs*g1.w + b1.w);
    *(ushort4*)xr       = o0;
    *(ushort4*)(xr + 4) = o1;
    int slot = lane ^ ((jl >> 3) & 7);
    *(ushort4*)&t[jl*512 + slot*8]     = o0;
    *(ushort4*)&t[jl*512 + slot*8 + 4] = o1;
  }
  __syncthreads();
  #pragma unroll
  for (int p = 0; p < 16; ++p){
    int s = p*256 + tt;
    int h = s >> 3;
    int jg = (s & 7) << 3;
    int gh = h >> 3, h0 = h & 7;
    int slot = gh ^ (jg >> 3);
    unsigned int e0 = t[(jg+0)*512 + slot*8 + h0];
    unsigned int e1 = t[(jg+1)*512 + slot*8 + h0];
    unsigned int e2 = t[(jg+2)*512 + slot*8 + h0];
    unsigned int e3 = t[(jg+3)*512 + slot*8 + h0];
    unsigned int e4 = t[(jg+4)*512 + slot*8 + h0];
    unsigned int e5 = t[(jg+5)*512 + slot*8 + h0];
    unsigned int e6 = t[(jg+6)*512 + slot*8 + h0];
    unsigned int e7 = t[(jg+7)*512 + slot*8 + h0];
    u32x4 d;
    d.x = e0 | (e1 << 16);
    d.y = e2 | (e3 << 16);
    d.z = e4 | (e5 << 16);
    d.w = e6 | (e7 << 16);
    *(u32x4*)(xT + ((size_t)h*RF + rr)*256 + j0 + jg) = d;
  }
}

// ---------- final layer: fused LayerNorm + output projection (fp32 out) ----------
__global__ __launch_bounds__(256) void k_lnout(const unsigned short* x, const float* gam,
                                               const float* bet, const float* Wpx,
                                               const float* bpx, float* out, int ly){
  int blk = blockIdx.x;                 // 1024 blocks, 64 rows each
  int tt = threadIdx.x;
  int lane = tt & 63, wv = tt >> 6;
  const float* gp  = gam + ly*DM + lane*8;
  const float* bp2 = bet + ly*DM + lane*8;
  float4 g0 = *(const float4*)gp,  g1 = *(const float4*)(gp + 4);
  float4 b0 = *(const float4*)bp2, b1 = *(const float4*)(bp2 + 4);
  for (int rw = 0; rw < 16; ++rw){
    int jl = wv*16 + rw;
    size_t m = (size_t)blk*64 + jl;
    const unsigned short* xr = x + m*DM + lane*8;
    ushort4 a0 = *(const ushort4*)xr;
    ushort4 a1 = *(const ushort4*)(xr + 4);
    float v[8];
    v[0]=us2f(a0.x); v[1]=us2f(a0.y); v[2]=us2f(a0.z); v[3]=us2f(a0.w);
    v[4]=us2f(a1.x); v[5]=us2f(a1.y); v[6]=us2f(a1.z); v[7]=us2f(a1.w);
    float s = 0.f, s2 = 0.f;
    #pragma unroll
    for (int i = 0; i < 8; ++i){ s += v[i]; s2 += v[i]*v[i]; }
    #pragma unroll
    for (int mm = 32; mm > 0; mm >>= 1){
      s  += __shfl_xor(s,  mm, 64);
      s2 += __shfl_xor(s2, mm, 64);
    }
    float mu  = s * (1.0f/DM);
    float var = s2 * (1.0f/DM) - mu*mu;
    float rs  = rsqrtf(var + 1e-5f);
    float vv[8];
    vv[0] = us2f(f2us((v[0]-mu)*rs*g0.x + b0.x));
    vv[1] = us2f(f2us((v[1]-mu)*rs*g0.y + b0.y));
    vv[2] = us2f(f2us((v[2]-mu)*rs*g0.z + b0.z));
    vv[3] = us2f(f2us((v[3]-mu)*rs*g0.w + b0.w));
    vv[4] = us2f(f2us((v[4]-mu)*rs*g1.x + b1.x));
    vv[5] = us2f(f2us((v[5]-mu)*rs*g1.y + b1.y));
    vv[6] = us2f(f2us((v[6]-mu)*rs*g1.z + b1.z));
    vv[7] = us2f(f2us((v[7]-mu)*rs*g1.w + b1.w));
    float p[6];
    #pragma unroll
    for (int c = 0; c < 6; ++c){
      const float* wr = Wpx + c*DM + lane*8;
      float4 w0 = *(const float4*)wr, w1 = *(const float4*)(wr + 4);
      float ss = vv[0]*w0.x + vv[1]*w0.y + vv[2]*w0.z + vv[3]*w0.w
               + vv[4]*w1.x + vv[5]*w1.y + vv[6]*w1.z + vv[7]*w1.w;
      #pragma unroll
      for (int mm = 32; mm > 0; mm >>= 1) ss += __shfl_xor(ss, mm, 64);
      p[c] = ss;
    }
    if (lane == 0){
      int b = (int)(m >> 12), l = (int)(m & 4095);
      #pragma unroll
      for (int c = 0; c < 3; ++c)
        out[((b*3 + c) << 12) + l] = p[c] + bpx[c];
      #pragma unroll
      for (int c = 3; c < 6; ++c)
        out[B_*3*LSEQ + ((b*3 + (c-3)) << 12) + l] = p[c] + bpx[c];
    }
  }
}

// ---------- launcher ----------
extern "C" void kernel_launch(void* const* d_in, const int* in_sizes, int n_in,
                              void* d_out, int out_size, void* d_ws, size_t ws_size,
                              hipStream_t stream) {
  const float* z     = (const float*)d_in[0];
  const float* Wp    = (const float*)d_in[1];
  const float* bp    = (const float*)d_in[2];
  const float* pos   = (const float*)d_in[3];
  const float* logdt = (const float*)d_in[4];
  const float* Cre   = (const float*)d_in[5];
  const float* Cim   = (const float*)d_in[6];
  const float* lAr   = (const float*)d_in[7];
  const float* Aimg  = (const float*)d_in[8];
  const float* Dsk   = (const float*)d_in[9];
  const float* Wc    = (const float*)d_in[10];
  const float* bc    = (const float*)d_in[11];
  const float* lng   = (const float*)d_in[12];
  const float* lnb   = (const float*)d_in[13];
  const float* Wpx   = (const float*)d_in[14];
  const float* bpx   = (const float*)d_in[15];
  float* out = (float*)d_out;

  char* ws = (char*)d_ws;
  unsigned short* x     = (unsigned short*)(ws);                 //  67,108,864
  unsigned short* xT    = (unsigned short*)(ws + 67108864);      //  67,108,864 (slotA: xT / ybuf)
  unsigned short* yT    = (unsigned short*)(ws + 134217728);     //  67,108,864 (slotB)
  unsigned short* ybuf  = xT;                                    //  alias: xT dead after k_p2
  unsigned short* V     = (unsigned short*)(ws + 218103808);     //  16,777,216
  unsigned short* Wv    = (unsigned short*)(ws + 234881024);     //  16,777,216
  unsigned short* KrevA = (unsigned short*)(ws + 251658240);     //     557,056
  unsigned short* KrevB = (unsigned short*)(ws + 252215296);     //     557,056
  float*          cf    = (float*)(ws + 252772352);              //   1,572,864
  unsigned short* Wcb   = (unsigned short*)(ws + 254345216);     //   4,194,304
  float*          pz    = (float*)(ws + 258539520);              //      32,768
  // total = 258,572,288 bytes

  k_coef  <<<256,  256, 0, stream>>>(logdt, Cre, Cim, lAr, Aimg, cf);
  k_cvt   <<<1024, 256, 0, stream>>>(Wc, Wcb);
  k_proj  <<<32,   256, 0, stream>>>(z, Wp, bp, pz);
  k_bcastT<<<1024, 256, 0, stream>>>(pz, pos, x, xT);
  k_kz    <<<272,  256, 0, stream>>>((u32x4*)KrevA);
  for (int ly = 0; ly < NL; ++ly){
    k_kv  <<<1024, 256, 0, stream>>>(logdt, lAr, Aimg, cf, KrevA, KrevB, V, ly);
    k_wv  <<<256,   64, 0, stream>>>(cf, Wv, ly);
    k_p2  <<<2048, 256, 0, stream>>>(xT, KrevA, KrevB, V, Wv, cf, Dsk, yT, ly);
    k_yT  <<<8192, 256, 0, stream>>>(yT, ybuf);
    k_gemm<<<2048, 256, 0, stream>>>(ybuf, Wcb, bc, x, ly);
    if (ly < NL-1) k_lnxT <<<1024, 256, 0, stream>>>(x, lng, lnb, xT, ly);
    else           k_lnout<<<1024, 256, 0, stream>>>(x, lng, lnb, Wpx, bpx, out, ly);
  }
}

// Round 19
// 1299.958 us; speedup vs baseline: 1.2190x; 1.2190x over previous
//
#include <hip/hip_runtime.h>
#include <hip/hip_bf16.h>

// ---------- types / constants ----------
typedef short bf16x8 __attribute__((ext_vector_type(8)));
typedef float f32x4 __attribute__((ext_vector_type(4)));
typedef unsigned int u32x4 __attribute__((ext_vector_type(4)));

#define B_   16
#define LSEQ 4096
#define DM   512
#define NST  32
#define NL   4
#define NCH  16
#define TC   256
#define RF   256            // full r count (r = b*16 + c)
#define KREVN 544
#define SZC  (NL*NST*DM)

__device__ __forceinline__ unsigned short f2us(float f){
  unsigned int x = __float_as_uint(f);
  x += 0x7fff + ((x >> 16) & 1);
  return (unsigned short)(x >> 16);
}
__device__ __forceinline__ float us2f(unsigned short u){
  return __uint_as_float(((unsigned int)u) << 16);
}

// ---------- K0: per-layer SSM coefficient planes (fp32) ----------
__global__ void k_coef(const float* log_dt, const float* C_re,
                       const float* C_im, const float* lAr,
                       const float* Aimg, float* coef){
  int tid = blockIdx.x * 256 + threadIdx.x;
  if (tid >= NL*NST*DM) return;
  int h  = tid & (DM-1);
  int n  = (tid >> 9) & (NST-1);
  int ly = tid >> 14;
  int ihn = (ly*DM + h)*NST + n;
  float dt  = expf(log_dt[ly*DM + h]);
  float Are = -expf(lAr[ihn]);
  float Aim = Aimg[ihn];
  float dar = dt*Are, dai = dt*Aim;
  float er  = expf(dar);
  float wre = er*cosf(dai), wim = er*sinf(dai);
  float Cr  = C_re[ihn], Ci = C_im[ihn];
  float e1r = wre - 1.0f, e1i = wim;
  float tr = Cr*e1r - Ci*e1i;
  float ti = Cr*e1i + Ci*e1r;
  float inv = 1.0f/(Are*Are + Aim*Aim);
  float ccr = (tr*Are + ti*Aim)*inv;
  float cci = (ti*Are - tr*Aim)*inv;
  float eT = expf(dar*(float)TC);
  float aT = dai*(float)TC;
  coef[0*SZC + tid] = wre;
  coef[1*SZC + tid] = wim;
  coef[2*SZC + tid] = 2.0f*ccr;
  coef[3*SZC + tid] = -2.0f*cci;
  coef[4*SZC + tid] = eT*cosf(aT);
  coef[5*SZC + tid] = eT*sinf(aT);
}

// ---------- Wconv fp32 -> bf16 ----------
__global__ void k_cvt(const float* Wc, unsigned short* Wcb){
  int tid = blockIdx.x * 256 + threadIdx.x;
  const float4 a = *(const float4*)(Wc + (size_t)tid*8);
  const float4 b = *(const float4*)(Wc + (size_t)tid*8 + 4);
  ushort4 r0, r1;
  r0.x = f2us(a.x); r0.y = f2us(a.y); r0.z = f2us(a.z); r0.w = f2us(a.w);
  r1.x = f2us(b.x); r1.y = f2us(b.y); r1.z = f2us(b.z); r1.w = f2us(b.w);
  *(ushort4*)(Wcb + (size_t)tid*8)     = r0;
  *(ushort4*)(Wcb + (size_t)tid*8 + 4) = r1;
}

// ---------- pz = z @ Wp^T + bp ----------
__global__ void k_proj(const float* z, const float* Wp, const float* bp, float* pz){
  int tid = blockIdx.x * 256 + threadIdx.x;
  if (tid >= B_*DM) return;
  int d = tid & (DM-1), b = tid >> 9;
  float acc = bp[d];
  const float* zr = z  + b*256;
  const float* wr = Wp + d*256;
  for (int k = 0; k < 256; ++k) acc = fmaf(zr[k], wr[k], acc);
  pz[tid] = acc;
}

// ---------- fused broadcast + transpose: x[m][h] = pz+pos (bf16) AND xT[h][r][j] ----------
__global__ __launch_bounds__(256) void k_bcastT(const float* pz, const float* pos,
                                                unsigned short* x, unsigned short* xT){
  __shared__ unsigned short t[64*512];
  int blk = blockIdx.x;                 // 1024 blocks
  int rr = blk >> 2;
  int j0 = (blk & 3) << 6;
  int tt = threadIdx.x;
  int lane = tt & 63, wv = tt >> 6;
  int b = (blk * 64) >> 12;             // batch, constant within block
  float4 p0 = *(const float4*)(pz + b*DM + lane*8);
  float4 p1 = *(const float4*)(pz + b*DM + lane*8 + 4);
  for (int rw = 0; rw < 16; ++rw){
    int jl = wv*16 + rw;
    size_t m = (size_t)blk*64 + jl;
    int l = (int)(m & 4095);
    const float* pe = pos + (size_t)l*DM + lane*8;
    float4 e0 = *(const float4*)pe;
    float4 e1 = *(const float4*)(pe + 4);
    ushort4 o0, o1;
    o0.x = f2us(p0.x+e0.x); o0.y = f2us(p0.y+e0.y); o0.z = f2us(p0.z+e0.z); o0.w = f2us(p0.w+e0.w);
    o1.x = f2us(p1.x+e1.x); o1.y = f2us(p1.y+e1.y); o1.z = f2us(p1.z+e1.z); o1.w = f2us(p1.w+e1.w);
    unsigned short* xr = x + m*DM + lane*8;
    *(ushort4*)xr       = o0;
    *(ushort4*)(xr + 4) = o1;
    int slot = lane ^ ((jl >> 3) & 7);
    *(ushort4*)&t[jl*512 + slot*8]     = o0;
    *(ushort4*)&t[jl*512 + slot*8 + 4] = o1;
  }
  __syncthreads();
  #pragma unroll
  for (int p = 0; p < 16; ++p){
    int s = p*256 + tt;
    int h = s >> 3;
    int jg = (s & 7) << 3;
    int gh = h >> 3, h0 = h & 7;
    int slot = gh ^ (jg >> 3);
    unsigned int e0 = t[(jg+0)*512 + slot*8 + h0];
    unsigned int e1 = t[(jg+1)*512 + slot*8 + h0];
    unsigned int e2 = t[(jg+2)*512 + slot*8 + h0];
    unsigned int e3 = t[(jg+3)*512 + slot*8 + h0];
    unsigned int e4 = t[(jg+4)*512 + slot*8 + h0];
    unsigned int e5 = t[(jg+5)*512 + slot*8 + h0];
    unsigned int e6 = t[(jg+6)*512 + slot*8 + h0];
    unsigned int e7 = t[(jg+7)*512 + slot*8 + h0];
    u32x4 d;
    d.x = e0 | (e1 << 16);
    d.y = e2 | (e3 << 16);
    d.z = e4 | (e5 << 16);
    d.w = e6 | (e7 << 16);
    *(u32x4*)(xT + ((size_t)h*RF + rr)*256 + j0 + jg) = d;
  }
}

// ---------- zero Krev buffers (both, contiguous; once) ----------
__global__ void k_kz(u32x4* p){
  p[blockIdx.x*256 + threadIdx.x] = (u32x4){0,0,0,0};
}

// ---------- Krev + V generation for layer ly ----------
__global__ void k_kv(const float* log_dt, const float* lAr, const float* Aimg,
                     const float* coef, unsigned short* KrevA, unsigned short* KrevB,
                     unsigned short* V, int ly){
  int tid = blockIdx.x*256 + threadIdx.x;
  int h   = tid >> 9;
  int tau = tid & 511;
  if (tau > 256) return;
  float taf = (float)tau;
  int hb = ly*DM + h;
  float dt = expf(log_dt[hb]);
  float kacc = 0.f;
  unsigned int vre[16], vim[16];
  #pragma unroll
  for (int n = 0; n < 32; n += 2){
    float vr[2], vi[2];
    #pragma unroll
    for (int s = 0; s < 2; ++s){
      int nn = n + s;
      int ihn = hb*NST + nn;
      float dar = -dt*expf(lAr[ihn]);
      float dai =  dt*Aimg[ihn];
      int o = ((ly*NST + nn) << 9) + h;
      float c2r = coef[2*SZC + o], c2i = coef[3*SZC + o];
      float er = expf(dar*taf);
      float Wr = er*cosf(dai*taf), Wi = er*sinf(dai*taf);
      float a = c2r*Wr + c2i*Wi;
      kacc += a;
      vr[s] = a;
      vi[s] = c2i*Wr - c2r*Wi;
    }
    vre[n>>1] = (unsigned int)f2us(vr[0]) | ((unsigned int)f2us(vr[1]) << 16);
    vim[n>>1] = (unsigned int)f2us(vi[0]) | ((unsigned int)f2us(vi[1]) << 16);
  }
  if (tau <= 255){
    KrevA[(size_t)h*KREVN + 255 - tau] = f2us(kacc);
    if (tau < 255) KrevB[(size_t)h*KREVN + 254 - tau] = f2us(kacc);
  }
  if (tau >= 1){
    unsigned short* vp = V + ((size_t)h*256 + (tau-1))*64;
    u32x4* vp4 = (u32x4*)vp;
    vp4[0] = (u32x4){vre[0],vre[1],vre[2],vre[3]};
    vp4[1] = (u32x4){vre[4],vre[5],vre[6],vre[7]};
    vp4[2] = (u32x4){vre[8],vre[9],vre[10],vre[11]};
    vp4[3] = (u32x4){vre[12],vre[13],vre[14],vre[15]};
    vp4[4] = (u32x4){vim[0],vim[1],vim[2],vim[3]};
    vp4[5] = (u32x4){vim[4],vim[5],vim[6],vim[7]};
    vp4[6] = (u32x4){vim[8],vim[9],vim[10],vim[11]};
    vp4[7] = (u32x4){vim[12],vim[13],vim[14],vim[15]};
  }
}

// ---------- Wv generation ----------
__global__ void k_wv(const float* coef, unsigned short* Wv, int ly){
  int tid = blockIdx.x*64 + threadIdx.x;
  int n = tid & 31, h = (tid >> 5) & 511;
  int o = ((ly*NST + n) << 9) + h;
  float wre = coef[0*SZC + o], wim = coef[1*SZC + o];
  float cr = 1.f, ci = 0.f;
  unsigned short* pr = Wv + ((size_t)h*64 + n)*256;
  unsigned short* pi = pr + (size_t)32*256;
  for (int blk = 0; blk < 16; ++blk){
    unsigned int pr_[8] = {0,0,0,0,0,0,0,0};
    unsigned int pi_[8] = {0,0,0,0,0,0,0,0};
    #pragma unroll
    for (int i = 0; i < 16; ++i){
      int pos = 15 - i;
      pr_[pos>>1] |= (unsigned int)f2us(cr) << ((pos&1)*16);
      pi_[pos>>1] |= (unsigned int)f2us(ci) << ((pos&1)*16);
      float nr = cr*wre - ci*wim;
      ci = cr*wim + ci*wre;
      cr = nr;
    }
    int jb = 240 - blk*16;
    *(u32x4*)(pr + jb)     = (u32x4){pr_[0],pr_[1],pr_[2],pr_[3]};
    *(u32x4*)(pr + jb + 8) = (u32x4){pr_[4],pr_[5],pr_[6],pr_[7]};
    *(u32x4*)(pi + jb)     = (u32x4){pi_[0],pi_[1],pi_[2],pi_[3]};
    *(u32x4*)(pi + jb + 8) = (u32x4){pi_[4],pi_[5],pi_[6],pi_[7]};
  }
}

// ---------- transpose yT[h][r][l] -> ybuf[m][h] (bf16, full) ----------
__global__ void k_yT(const unsigned short* yT, unsigned short* ybuf){
  __shared__ unsigned short t[64][72];
  int blk = blockIdx.x;
  int h0 = (blk & 7) << 6;
  int l0 = ((blk >> 3) & 3) << 6;
  int rg = blk >> 5;                     // 0..255
  int tt = threadIdx.x;
  #pragma unroll
  for (int p = 0; p < 2; ++p){
    int e = p*2048 + tt*8;
    int row = e >> 6, col = e & 63;
    *(uint4*)&t[row][col] = *(const uint4*)(yT + ((size_t)(h0+row)*RF + rg)*256 + l0 + col);
  }
  __syncthreads();
  #pragma unroll
  for (int p = 0; p < 2; ++p){
    int e = p*2048 + tt*8;
    int orow = e >> 6, oc = e & 63;
    unsigned int d0 = (unsigned int)t[oc+0][orow] | ((unsigned int)t[oc+1][orow] << 16);
    unsigned int d1 = (unsigned int)t[oc+2][orow] | ((unsigned int)t[oc+3][orow] << 16);
    unsigned int d2 = (unsigned int)t[oc+4][orow] | ((unsigned int)t[oc+5][orow] << 16);
    unsigned int d3 = (unsigned int)t[oc+6][orow] | ((unsigned int)t[oc+7][orow] << 16);
    *(u32x4*)(ybuf + ((size_t)(rg*256 + l0 + orow))*DM + h0 + oc) = (u32x4){d0,d1,d2,d3};
  }
}

// ---------- pass2: fused local-state GEMM + in-block scan + Toeplitz/state GEMM ----------
__global__ __launch_bounds__(256) void k_p2(const unsigned short* xT, const unsigned short* KrevA,
      const unsigned short* KrevB, const unsigned short* V, const unsigned short* Wv,
      const float* coef, const float* Dsk, unsigned short* yT, int ly){
  __shared__ unsigned short us[64*256];
  __shared__ unsigned short st[64*64];
  int blk = blockIdx.x;
  int h  = blk >> 2;
  int r0 = (blk & 3) << 6;
  int tt = threadIdx.x;
  int lane = tt & 63, wv = tt >> 6;
  int la = lane & 15, kb = lane >> 4;
  const unsigned short* xp = xT + ((size_t)h*RF + r0)*256;
  #pragma unroll
  for (int p = 0; p < 8; ++p){
    int e = (p*256 + tt)*8;
    int r = e >> 8, j = e & 255;
    int g = ((j >> 3) ^ (r & 7));
    *(uint4*)&us[r*256 + g*8] = *(const uint4*)(xp + r*256 + j);
  }
  __syncthreads();
  // local states: S[rl][m2] = sum_j u[rl][j] * Wv[m2][j]
  {
    int wr = wv & 1, wm = wv >> 1;
    f32x4 sacc[2][2] = {};
    const unsigned short* wvp = Wv + (size_t)h*64*256;
    for (int j0 = 0; j0 < 256; j0 += 32){
      bf16x8 uf[2], wf[2];
      #pragma unroll
      for (int i = 0; i < 2; ++i){
        int r = wr*32 + i*16 + la;
        int g = (((j0 + kb*8) >> 3) ^ (r & 7));
        uf[i] = *(const bf16x8*)&us[r*256 + g*8];
      }
      #pragma unroll
      for (int i = 0; i < 2; ++i){
        int m2 = wm*32 + i*16 + la;
        wf[i] = *(const bf16x8*)(wvp + m2*256 + j0 + kb*8);
      }
      #pragma unroll
      for (int a = 0; a < 2; ++a)
        #pragma unroll
        for (int b = 0; b < 2; ++b)
          sacc[a][b] = __builtin_amdgcn_mfma_f32_16x16x32_bf16(uf[a], wf[b], sacc[a][b], 0, 0, 0);
    }
    #pragma unroll
    for (int a = 0; a < 2; ++a)
      #pragma unroll
      for (int b = 0; b < 2; ++b)
        #pragma unroll
        for (int q = 0; q < 4; ++q){
          int rl = wr*32 + a*16 + kb*4 + q;
          int m2 = wm*32 + b*16 + la;
          int slot = ((m2 >> 3) ^ (rl & 7));
          st[rl*64 + slot*8 + (m2 & 7)] = f2us(sacc[a][b][q]);
        }
  }
  __syncthreads();
  // in-block scan
  {
    int nm = lane & 31;
    float sgn = (lane < 32) ? -1.f : 1.f;
    int o = ((ly*NST + nm) << 9) + h;
    float wTre = coef[4*SZC + o], wTim = coef[5*SZC + o];
    float S = 0.f;
    int slot0 = lane >> 3, c0 = lane & 7;
    for (int c = 0; c < NCH; ++c){
      int rl = wv*16 + c;
      int idx = rl*64 + ((slot0 ^ (rl & 7)) << 3) + c0;
      float loc = us2f(st[idx]);
      st[idx] = f2us(S);
      float prt = __shfl_xor(S, 32);
      S = fmaf(wTre, S, fmaf(sgn*wTim, prt, loc));
    }
  }
  __syncthreads();
  int wl = wv >> 1, wr = wv & 1;
  const unsigned short* KA = KrevA + (size_t)h*KREVN;
  const unsigned short* KB = KrevB + (size_t)h*KREVN;
  const unsigned short* Vp = V + (size_t)h*256*64;
  float Dv = Dsk[ly*DM + h];
  unsigned short* yp = yT + (size_t)h*RF*256;
  for (int lt = 0; lt < 4; ++lt){
    int l0w = lt*64 + wl*32;
    f32x4 acc[2][2] = {};
    int jsteps = (l0w >> 5) + 1;
    for (int js = 0; js < jsteps; ++js){
      int j0 = js*32;
      bf16x8 uf[2], tf[2];
      #pragma unroll
      for (int i = 0; i < 2; ++i){
        int rb = wr*32 + i*16 + la;
        int g = (((j0 + kb*8) >> 3) ^ (rb & 7));
        uf[i] = *(const bf16x8*)&us[rb*256 + g*8];
      }
      #pragma unroll
      for (int i = 0; i < 2; ++i){
        int l = l0w + i*16 + la;
        int idx = 255 - l + j0 + kb*8;
        const unsigned short* base = (idx & 1) ? (KB + idx - 1) : (KA + idx);
        unsigned int d0 = *(const unsigned int*)(base);
        unsigned int d1 = *(const unsigned int*)(base + 2);
        unsigned int d2 = *(const unsigned int*)(base + 4);
        unsigned int d3 = *(const unsigned int*)(base + 6);
        tf[i] = __builtin_bit_cast(bf16x8, (u32x4){d0,d1,d2,d3});
      }
      #pragma unroll
      for (int a = 0; a < 2; ++a)
        #pragma unroll
        for (int b = 0; b < 2; ++b)
          acc[a][b] = __builtin_amdgcn_mfma_f32_16x16x32_bf16(uf[a], tf[b], acc[a][b], 0, 0, 0);
    }
    #pragma unroll
    for (int ms = 0; ms < 2; ++ms){
      int m0 = ms*32;
      bf16x8 sf[2], vf[2];
      #pragma unroll
      for (int i = 0; i < 2; ++i){
        int rb = wr*32 + i*16 + la;
        int slot = ((m0 + kb*8) >> 3) ^ (rb & 7);
        sf[i] = *(const bf16x8*)&st[rb*64 + slot*8];
      }
      #pragma unroll
      for (int i = 0; i < 2; ++i){
        int l = l0w + i*16 + la;
        vf[i] = *(const bf16x8*)(Vp + l*64 + m0 + kb*8);
      }
      #pragma unroll
      for (int a = 0; a < 2; ++a)
        #pragma unroll
        for (int b = 0; b < 2; ++b)
          acc[a][b] = __builtin_amdgcn_mfma_f32_16x16x32_bf16(sf[a], vf[b], acc[a][b], 0, 0, 0);
    }
    #pragma unroll
    for (int a = 0; a < 2; ++a)
      #pragma unroll
      for (int b = 0; b < 2; ++b)
        #pragma unroll
        for (int q = 0; q < 4; ++q){
          int rb = wr*32 + a*16 + kb*4 + q;
          int l  = l0w + b*16 + la;
          int g = ((l >> 3) ^ (rb & 7));
          float u = us2f(us[rb*256 + g*8 + (l & 7)]);
          float y = acc[a][b][q] + Dv*u;
          float gl = 0.5f*y*(1.0f + erff(y*0.70710678118654752f));
          yp[(r0 + rb)*256 + l] = f2us(gl);
        }
  }
}

// ---------- GLU GEMM: reg-staged BK=64 (0 bank conflicts) + XCD swizzle [r13/r17 body] ----------
__global__ __launch_bounds__(256,2) void k_gemm(const unsigned short* A, const unsigned short* Bw,
                                                const float* bias, unsigned short* x, int ly){
  __shared__ short As[128*64];
  __shared__ short Bs[2][128*64];
  const int K = 512;
  int bid = blockIdx.x;
  int swz = (bid & 7) * 256 + (bid >> 3);     // XCD-aware bijective swizzle (2048 = 8*256)
  int Mt = swz >> 2;
  int Nt = swz & 3;
  int lane = threadIdx.x & 63, wv = threadIdx.x >> 6;
  int wm = wv >> 1, wn = wv & 1;
  f32x4 acc[2][4][4] = {};
  const unsigned short* Ag = A  + (size_t)Mt * 128 * K;
  const unsigned short* B0 = Bw + (size_t)ly * 1024 * K + (size_t)Nt * 128 * K;
  const unsigned short* B1 = B0 + (size_t)512 * K;
  for (int k0 = 0; k0 < K; k0 += 64){
    __syncthreads();
    #pragma unroll
    for (int p = 0; p < 4; ++p){
      int e = (p*256 + threadIdx.x) * 8;
      int row = e >> 6, k = e & 63;
      int sw = ((k >> 3) ^ (row & 7)) << 3;
      *(uint4*)(&As[row*64 + sw])    = *(const uint4*)(Ag + (size_t)row*K + k0 + k);
      *(uint4*)(&Bs[0][row*64 + sw]) = *(const uint4*)(B0 + (size_t)row*K + k0 + k);
      *(uint4*)(&Bs[1][row*64 + sw]) = *(const uint4*)(B1 + (size_t)row*K + k0 + k);
    }
    __syncthreads();
    #pragma unroll
    for (int kk = 0; kk < 64; kk += 32){
      int kb = (kk >> 3) + (lane >> 4);
      bf16x8 af[4], b0[4], b1[4];
      #pragma unroll
      for (int i = 0; i < 4; ++i){
        int ra = wm*64 + i*16 + (lane & 15);
        af[i] = *(const bf16x8*)(&As[ra*64 + ((kb ^ (ra & 7)) << 3)]);
        int rb = wn*64 + i*16 + (lane & 15);
        b0[i] = *(const bf16x8*)(&Bs[0][rb*64 + ((kb ^ (rb & 7)) << 3)]);
        b1[i] = *(const bf16x8*)(&Bs[1][rb*64 + ((kb ^ (rb & 7)) << 3)]);
      }
      #pragma unroll
      for (int i = 0; i < 4; ++i)
        #pragma unroll
        for (int j = 0; j < 4; ++j){
          acc[0][i][j] = __builtin_amdgcn_mfma_f32_16x16x32_bf16(af[i], b0[j], acc[0][i][j], 0, 0, 0);
          acc[1][i][j] = __builtin_amdgcn_mfma_f32_16x16x32_bf16(af[i], b1[j], acc[1][i][j], 0, 0, 0);
        }
    }
  }
  #pragma unroll
  for (int j = 0; j < 4; ++j){
    int n = Nt*128 + wn*64 + j*16 + (lane & 15);
    float ba = bias[ly*1024 + n];
    float bg = bias[ly*1024 + 512 + n];
    #pragma unroll
    for (int i = 0; i < 4; ++i){
      int mb = Mt*128 + wm*64 + i*16 + ((lane >> 4) << 2);
      #pragma unroll
      for (int q = 0; q < 4; ++q){
        float a = acc[0][i][j][q] + ba;
        float g = acc[1][i][j][q] + bg;
        float glu = a / (1.0f + expf(-g));
        size_t off = (size_t)(mb + q) * DM + n;
        x[off] = f2us(us2f(x[off]) + glu);
      }
    }
  }
}

// ---------- fused LayerNorm + transpose (layers 0..NL-2) ----------
__global__ __launch_bounds__(256) void k_lnxT(unsigned short* x, const float* gam,
                                              const float* bet, unsigned short* xT, int ly){
  __shared__ unsigned short t[64*512];
  int blk = blockIdx.x;                 // 1024 blocks
  int rr = blk >> 2;
  int j0 = (blk & 3) << 6;
  int tt = threadIdx.x;
  int lane = tt & 63, wv = tt >> 6;
  const float* gp  = gam + ly*DM + lane*8;
  const float* bp2 = bet + ly*DM + lane*8;
  float4 g0 = *(const float4*)gp,  g1 = *(const float4*)(gp + 4);
  float4 b0 = *(const float4*)bp2, b1 = *(const float4*)(bp2 + 4);
  for (int rw = 0; rw < 16; ++rw){
    int jl = wv*16 + rw;
    size_t m = (size_t)blk*64 + jl;
    unsigned short* xr = x + m*DM + lane*8;
    ushort4 a0 = *(const ushort4*)xr;
    ushort4 a1 = *(const ushort4*)(xr + 4);
    float v[8];
    v[0]=us2f(a0.x); v[1]=us2f(a0.y); v[2]=us2f(a0.z); v[3]=us2f(a0.w);
    v[4]=us2f(a1.x); v[5]=us2f(a1.y); v[6]=us2f(a1.z); v[7]=us2f(a1.w);
    float s = 0.f, s2 = 0.f;
    #pragma unroll
    for (int i = 0; i < 8; ++i){ s += v[i]; s2 += v[i]*v[i]; }
    #pragma unroll
    for (int mm = 32; mm > 0; mm >>= 1){
      s  += __shfl_xor(s,  mm, 64);
      s2 += __shfl_xor(s2, mm, 64);
    }
    float mu  = s * (1.0f/DM);
    float var = s2 * (1.0f/DM) - mu*mu;
    float rs  = rsqrtf(var + 1e-5f);
    ushort4 o0, o1;
    o0.x = f2us((v[0]-mu)*rs*g0.x + b0.x);
    o0.y = f2us((v[1]-mu)*rs*g0.y + b0.y);
    o0.z = f2us((v[2]-mu)*rs*g0.z + b0.z);
    o0.w = f2us((v[3]-mu)*rs*g0.w + b0.w);
    o1.x = f2us((v[4]-mu)*rs*g1.x + b1.x);
    o1.y = f2us((v[5]-mu)*rs*g1.y + b1.y);
    o1.z = f2us((v[6]-mu)*rs*g1.z + b1.z);
    o1.w = f2us((v[7]-mu)*rs*g1.w + b1.w);
    *(ushort4*)xr       = o0;
    *(ushort4*)(xr + 4) = o1;
    int slot = lane ^ ((jl >> 3) & 7);
    *(ushort4*)&t[jl*512 + slot*8]     = o0;
    *(ushort4*)&t[jl*512 + slot*8 + 4] = o1;
  }
  __syncthreads();
  #pragma unroll
  for (int p = 0; p < 16; ++p){
    int s = p*256 + tt;
    int h = s >> 3;
    int jg = (s & 7) << 3;
    int gh = h >> 3, h0 = h & 7;
    int slot = gh ^ (jg >> 3);
    unsigned int e0 = t[(jg+0)*512 + slot*8 + h0];
    unsigned int e1 = t[(jg+1)*512 + slot*8 + h0];
    unsigned int e2 = t[(jg+2)*512 + slot*8 + h0];
    unsigned int e3 = t[(jg+3)*512 + slot*8 + h0];
    unsigned int e4 = t[(jg+4)*512 + slot*8 + h0];
    unsigned int e5 = t[(jg+5)*512 + slot*8 + h0];
    unsigned int e6 = t[(jg+6)*512 + slot*8 + h0];
    unsigned int e7 = t[(jg+7)*512 + slot*8 + h0];
    u32x4 d;
    d.x = e0 | (e1 << 16);
    d.y = e2 | (e3 << 16);
    d.z = e4 | (e5 << 16);
    d.w = e6 | (e7 << 16);
    *(u32x4*)(xT + ((size_t)h*RF + rr)*256 + j0 + jg) = d;
  }
}

// ---------- final layer: fused LayerNorm + output projection (fp32 out) ----------
__global__ __launch_bounds__(256) void k_lnout(const unsigned short* x, const float* gam,
                                               const float* bet, const float* Wpx,
                                               const float* bpx, float* out, int ly){
  int blk = blockIdx.x;                 // 1024 blocks, 64 rows each
  int tt = threadIdx.x;
  int lane = tt & 63, wv = tt >> 6;
  const float* gp  = gam + ly*DM + lane*8;
  const float* bp2 = bet + ly*DM + lane*8;
  float4 g0 = *(const float4*)gp,  g1 = *(const float4*)(gp + 4);
  float4 b0 = *(const float4*)bp2, b1 = *(const float4*)(bp2 + 4);
  for (int rw = 0; rw < 16; ++rw){
    int jl = wv*16 + rw;
    size_t m = (size_t)blk*64 + jl;
    const unsigned short* xr = x + m*DM + lane*8;
    ushort4 a0 = *(const ushort4*)xr;
    ushort4 a1 = *(const ushort4*)(xr + 4);
    float v[8];
    v[0]=us2f(a0.x); v[1]=us2f(a0.y); v[2]=us2f(a0.z); v[3]=us2f(a0.w);
    v[4]=us2f(a1.x); v[5]=us2f(a1.y); v[6]=us2f(a1.z); v[7]=us2f(a1.w);
    float s = 0.f, s2 = 0.f;
    #pragma unroll
    for (int i = 0; i < 8; ++i){ s += v[i]; s2 += v[i]*v[i]; }
    #pragma unroll
    for (int mm = 32; mm > 0; mm >>= 1){
      s  += __shfl_xor(s,  mm, 64);
      s2 += __shfl_xor(s2, mm, 64);
    }
    float mu  = s * (1.0f/DM);
    float var = s2 * (1.0f/DM) - mu*mu;
    float rs  = rsqrtf(var + 1e-5f);
    float vv[8];
    vv[0] = us2f(f2us((v[0]-mu)*rs*g0.x + b0.x));
    vv[1] = us2f(f2us((v[1]-mu)*rs*g0.y + b0.y));
    vv[2] = us2f(f2us((v[2]-mu)*rs*g0.z + b0.z));
    vv[3] = us2f(f2us((v[3]-mu)*rs*g0.w + b0.w));
    vv[4] = us2f(f2us((v[4]-mu)*rs*g1.x + b1.x));
    vv[5] = us2f(f2us((v[5]-mu)*rs*g1.y + b1.y));
    vv[6] = us2f(f2us((v[6]-mu)*rs*g1.z + b1.z));
    vv[7] = us2f(f2us((v[7]-mu)*rs*g1.w + b1.w));
    float p[6];
    #pragma unroll
    for (int c = 0; c < 6; ++c){
      const float* wr = Wpx + c*DM + lane*8;
      float4 w0 = *(const float4*)wr, w1 = *(const float4*)(wr + 4);
      float ss = vv[0]*w0.x + vv[1]*w0.y + vv[2]*w0.z + vv[3]*w0.w
               + vv[4]*w1.x + vv[5]*w1.y + vv[6]*w1.z + vv[7]*w1.w;
      #pragma unroll
      for (int mm = 32; mm > 0; mm >>= 1) ss += __shfl_xor(ss, mm, 64);
      p[c] = ss;
    }
    if (lane == 0){
      int b = (int)(m >> 12), l = (int)(m & 4095);
      #pragma unroll
      for (int c = 0; c < 3; ++c)
        out[((b*3 + c) << 12) + l] = p[c] + bpx[c];
      #pragma unroll
      for (int c = 3; c < 6; ++c)
        out[B_*3*LSEQ + ((b*3 + (c-3)) << 12) + l] = p[c] + bpx[c];
    }
  }
}

// ---------- launcher ----------
extern "C" void kernel_launch(void* const* d_in, const int* in_sizes, int n_in,
                              void* d_out, int out_size, void* d_ws, size_t ws_size,
                              hipStream_t stream) {
  const float* z     = (const float*)d_in[0];
  const float* Wp    = (const float*)d_in[1];
  const float* bp    = (const float*)d_in[2];
  const float* pos   = (const float*)d_in[3];
  const float* logdt = (const float*)d_in[4];
  const float* Cre   = (const float*)d_in[5];
  const float* Cim   = (const float*)d_in[6];
  const float* lAr   = (const float*)d_in[7];
  const float* Aimg  = (const float*)d_in[8];
  const float* Dsk   = (const float*)d_in[9];
  const float* Wc    = (const float*)d_in[10];
  const float* bc    = (const float*)d_in[11];
  const float* lng   = (const float*)d_in[12];
  const float* lnb   = (const float*)d_in[13];
  const float* Wpx   = (const float*)d_in[14];
  const float* bpx   = (const float*)d_in[15];
  float* out = (float*)d_out;

  char* ws = (char*)d_ws;
  unsigned short* x     = (unsigned short*)(ws);                 //  67,108,864
  unsigned short* xT    = (unsigned short*)(ws + 67108864);      //  67,108,864 (slotA: xT / ybuf)
  unsigned short* yT    = (unsigned short*)(ws + 134217728);     //  67,108,864 (slotB)
  unsigned short* ybuf  = xT;                                    //  alias: xT dead after k_p2
  unsigned short* V     = (unsigned short*)(ws + 218103808);     //  16,777,216
  unsigned short* Wv    = (unsigned short*)(ws + 234881024);     //  16,777,216
  unsigned short* KrevA = (unsigned short*)(ws + 251658240);     //     557,056
  unsigned short* KrevB = (unsigned short*)(ws + 252215296);     //     557,056
  float*          cf    = (float*)(ws + 252772352);              //   1,572,864
  unsigned short* Wcb   = (unsigned short*)(ws + 254345216);     //   4,194,304
  float*          pz    = (float*)(ws + 258539520);              //      32,768
  // total = 258,572,288 bytes

  k_coef  <<<256,  256, 0, stream>>>(logdt, Cre, Cim, lAr, Aimg, cf);
  k_cvt   <<<1024, 256, 0, stream>>>(Wc, Wcb);
  k_proj  <<<32,   256, 0, stream>>>(z, Wp, bp, pz);
  k_bcastT<<<1024, 256, 0, stream>>>(pz, pos, x, xT);
  k_kz    <<<272,  256, 0, stream>>>((u32x4*)KrevA);
  for (int ly = 0; ly < NL; ++ly){
    k_kv  <<<1024, 256, 0, stream>>>(logdt, lAr, Aimg, cf, KrevA, KrevB, V, ly);
    k_wv  <<<256,   64, 0, stream>>>(cf, Wv, ly);
    k_p2  <<<2048, 256, 0, stream>>>(xT, KrevA, KrevB, V, Wv, cf, Dsk, yT, ly);
    k_yT  <<<8192, 256, 0, stream>>>(yT, ybuf);
    k_gemm<<<2048, 256, 0, stream>>>(ybuf, Wcb, bc, x, ly);
    if (ly < NL-1) k_lnxT <<<1024, 256, 0, stream>>>(x, lng, lnb, xT, ly);
    else           k_lnout<<<1024, 256, 0, stream>>>(x, lng, lnb, Wpx, bpx, out, ly);
  }
}

// Round 20
// 1283.475 us; speedup vs baseline: 1.2347x; 1.0128x over previous
//
#include <hip/hip_runtime.h>
#include <hip/hip_bf16.h>

// ---------- types / constants ----------
typedef short bf16x8 __attribute__((ext_vector_type(8)));
typedef float f32x4 __attribute__((ext_vector_type(4)));
typedef unsigned int u32x4 __attribute__((ext_vector_type(4)));

#define B_   16
#define LSEQ 4096
#define DM   512
#define NST  32
#define NL   4
#define NCH  16
#define TC   256
#define RF   256            // full r count (r = b*16 + c)
#define KREVN 544
#define SZC  (NL*NST*DM)

__device__ __forceinline__ unsigned short f2us(float f){
  unsigned int x = __float_as_uint(f);
  x += 0x7fff + ((x >> 16) & 1);
  return (unsigned short)(x >> 16);
}
__device__ __forceinline__ float us2f(unsigned short u){
  return __uint_as_float(((unsigned int)u) << 16);
}

// ---------- fused preamble: coef | Wconv->bf16 | pz | Krev zero (independent ranges) ----------
__global__ void k_pre(const float* log_dt, const float* C_re, const float* C_im,
                      const float* lAr, const float* Aimg, float* coef,
                      const float* Wc, unsigned short* Wcb,
                      const float* z, const float* Wp, const float* bp, float* pz,
                      u32x4* krz){
  int blk = blockIdx.x;
  int tt  = threadIdx.x;
  if (blk < 256){
    // ---- coef body (tid over 65536) ----
    int tid = blk * 256 + tt;
    if (tid >= NL*NST*DM) return;
    int h  = tid & (DM-1);
    int n  = (tid >> 9) & (NST-1);
    int ly = tid >> 14;
    int ihn = (ly*DM + h)*NST + n;
    float dt  = expf(log_dt[ly*DM + h]);
    float Are = -expf(lAr[ihn]);
    float Aim = Aimg[ihn];
    float dar = dt*Are, dai = dt*Aim;
    float er  = expf(dar);
    float wre = er*cosf(dai), wim = er*sinf(dai);
    float Cr  = C_re[ihn], Ci = C_im[ihn];
    float e1r = wre - 1.0f, e1i = wim;
    float tr = Cr*e1r - Ci*e1i;
    float ti = Cr*e1i + Ci*e1r;
    float inv = 1.0f/(Are*Are + Aim*Aim);
    float ccr = (tr*Are + ti*Aim)*inv;
    float cci = (ti*Are - tr*Aim)*inv;
    float eT = expf(dar*(float)TC);
    float aT = dai*(float)TC;
    coef[0*SZC + tid] = wre;
    coef[1*SZC + tid] = wim;
    coef[2*SZC + tid] = 2.0f*ccr;
    coef[3*SZC + tid] = -2.0f*cci;
    coef[4*SZC + tid] = eT*cosf(aT);
    coef[5*SZC + tid] = eT*sinf(aT);
  } else if (blk < 1280){
    // ---- cvt body (tid over 262144 x8) ----
    int tid = (blk - 256) * 256 + tt;
    const float4 a = *(const float4*)(Wc + (size_t)tid*8);
    const float4 b = *(const float4*)(Wc + (size_t)tid*8 + 4);
    ushort4 r0, r1;
    r0.x = f2us(a.x); r0.y = f2us(a.y); r0.z = f2us(a.z); r0.w = f2us(a.w);
    r1.x = f2us(b.x); r1.y = f2us(b.y); r1.z = f2us(b.z); r1.w = f2us(b.w);
    *(ushort4*)(Wcb + (size_t)tid*8)     = r0;
    *(ushort4*)(Wcb + (size_t)tid*8 + 4) = r1;
  } else if (blk < 1312){
    // ---- proj body ----
    int tid = (blk - 1280) * 256 + tt;
    if (tid >= B_*DM) return;
    int d = tid & (DM-1), b = tid >> 9;
    float acc = bp[d];
    const float* zr = z  + b*256;
    const float* wr = Wp + d*256;
    for (int k = 0; k < 256; ++k) acc = fmaf(zr[k], wr[k], acc);
    pz[tid] = acc;
  } else {
    // ---- Krev zero body (272 blocks worth) ----
    krz[(blk - 1312)*256 + tt] = (u32x4){0,0,0,0};
  }
}

// ---------- fused broadcast + transpose: x[m][h] = pz+pos (bf16) AND xT[h][r][j] ----------
__global__ __launch_bounds__(256) void k_bcastT(const float* pz, const float* pos,
                                                unsigned short* x, unsigned short* xT){
  __shared__ unsigned short t[64*512];
  int blk = blockIdx.x;                 // 1024 blocks
  int rr = blk >> 2;
  int j0 = (blk & 3) << 6;
  int tt = threadIdx.x;
  int lane = tt & 63, wv = tt >> 6;
  int b = (blk * 64) >> 12;             // batch, constant within block
  float4 p0 = *(const float4*)(pz + b*DM + lane*8);
  float4 p1 = *(const float4*)(pz + b*DM + lane*8 + 4);
  for (int rw = 0; rw < 16; ++rw){
    int jl = wv*16 + rw;
    size_t m = (size_t)blk*64 + jl;
    int l = (int)(m & 4095);
    const float* pe = pos + (size_t)l*DM + lane*8;
    float4 e0 = *(const float4*)pe;
    float4 e1 = *(const float4*)(pe + 4);
    ushort4 o0, o1;
    o0.x = f2us(p0.x+e0.x); o0.y = f2us(p0.y+e0.y); o0.z = f2us(p0.z+e0.z); o0.w = f2us(p0.w+e0.w);
    o1.x = f2us(p1.x+e1.x); o1.y = f2us(p1.y+e1.y); o1.z = f2us(p1.z+e1.z); o1.w = f2us(p1.w+e1.w);
    unsigned short* xr = x + m*DM + lane*8;
    *(ushort4*)xr       = o0;
    *(ushort4*)(xr + 4) = o1;
    int slot = lane ^ ((jl >> 3) & 7);
    *(ushort4*)&t[jl*512 + slot*8]     = o0;
    *(ushort4*)&t[jl*512 + slot*8 + 4] = o1;
  }
  __syncthreads();
  #pragma unroll
  for (int p = 0; p < 16; ++p){
    int s = p*256 + tt;
    int h = s >> 3;
    int jg = (s & 7) << 3;
    int gh = h >> 3, h0 = h & 7;
    int slot = gh ^ (jg >> 3);
    unsigned int e0 = t[(jg+0)*512 + slot*8 + h0];
    unsigned int e1 = t[(jg+1)*512 + slot*8 + h0];
    unsigned int e2 = t[(jg+2)*512 + slot*8 + h0];
    unsigned int e3 = t[(jg+3)*512 + slot*8 + h0];
    unsigned int e4 = t[(jg+4)*512 + slot*8 + h0];
    unsigned int e5 = t[(jg+5)*512 + slot*8 + h0];
    unsigned int e6 = t[(jg+6)*512 + slot*8 + h0];
    unsigned int e7 = t[(jg+7)*512 + slot*8 + h0];
    u32x4 d;
    d.x = e0 | (e1 << 16);
    d.y = e2 | (e3 << 16);
    d.z = e4 | (e5 << 16);
    d.w = e6 | (e7 << 16);
    *(u32x4*)(xT + ((size_t)h*RF + rr)*256 + j0 + jg) = d;
  }
}

// ---------- fused Krev+V | Wv generation for layer ly ----------
__global__ void k_kvw(const float* log_dt, const float* lAr, const float* Aimg,
                      const float* coef, unsigned short* KrevA, unsigned short* KrevB,
                      unsigned short* V, unsigned short* Wv, int ly){
  int blk = blockIdx.x;
  int tt  = threadIdx.x;
  if (blk < 1024){
    // ---- kv body ----
    int tid = blk*256 + tt;
    int h   = tid >> 9;
    int tau = tid & 511;
    if (tau > 256) return;
    float taf = (float)tau;
    int hb = ly*DM + h;
    float dt = expf(log_dt[hb]);
    float kacc = 0.f;
    unsigned int vre[16], vim[16];
    #pragma unroll
    for (int n = 0; n < 32; n += 2){
      float vr[2], vi[2];
      #pragma unroll
      for (int s = 0; s < 2; ++s){
        int nn = n + s;
        int ihn = hb*NST + nn;
        float dar = -dt*expf(lAr[ihn]);
        float dai =  dt*Aimg[ihn];
        int o = ((ly*NST + nn) << 9) + h;
        float c2r = coef[2*SZC + o], c2i = coef[3*SZC + o];
        float er = expf(dar*taf);
        float Wr = er*cosf(dai*taf), Wi = er*sinf(dai*taf);
        float a = c2r*Wr + c2i*Wi;
        kacc += a;
        vr[s] = a;
        vi[s] = c2i*Wr - c2r*Wi;
      }
      vre[n>>1] = (unsigned int)f2us(vr[0]) | ((unsigned int)f2us(vr[1]) << 16);
      vim[n>>1] = (unsigned int)f2us(vi[0]) | ((unsigned int)f2us(vi[1]) << 16);
    }
    if (tau <= 255){
      KrevA[(size_t)h*KREVN + 255 - tau] = f2us(kacc);
      if (tau < 255) KrevB[(size_t)h*KREVN + 254 - tau] = f2us(kacc);
    }
    if (tau >= 1){
      unsigned short* vp = V + ((size_t)h*256 + (tau-1))*64;
      u32x4* vp4 = (u32x4*)vp;
      vp4[0] = (u32x4){vre[0],vre[1],vre[2],vre[3]};
      vp4[1] = (u32x4){vre[4],vre[5],vre[6],vre[7]};
      vp4[2] = (u32x4){vre[8],vre[9],vre[10],vre[11]};
      vp4[3] = (u32x4){vre[12],vre[13],vre[14],vre[15]};
      vp4[4] = (u32x4){vim[0],vim[1],vim[2],vim[3]};
      vp4[5] = (u32x4){vim[4],vim[5],vim[6],vim[7]};
      vp4[6] = (u32x4){vim[8],vim[9],vim[10],vim[11]};
      vp4[7] = (u32x4){vim[12],vim[13],vim[14],vim[15]};
    }
  } else {
    // ---- wv body (16384 threads over 64 blocks) ----
    int tid = (blk - 1024)*256 + tt;
    int n = tid & 31, h = (tid >> 5) & 511;
    int o = ((ly*NST + n) << 9) + h;
    float wre = coef[0*SZC + o], wim = coef[1*SZC + o];
    float cr = 1.f, ci = 0.f;
    unsigned short* pr = Wv + ((size_t)h*64 + n)*256;
    unsigned short* pi = pr + (size_t)32*256;
    for (int b = 0; b < 16; ++b){
      unsigned int pr_[8] = {0,0,0,0,0,0,0,0};
      unsigned int pi_[8] = {0,0,0,0,0,0,0,0};
      #pragma unroll
      for (int i = 0; i < 16; ++i){
        int pos = 15 - i;
        pr_[pos>>1] |= (unsigned int)f2us(cr) << ((pos&1)*16);
        pi_[pos>>1] |= (unsigned int)f2us(ci) << ((pos&1)*16);
        float nr = cr*wre - ci*wim;
        ci = cr*wim + ci*wre;
        cr = nr;
      }
      int jb = 240 - b*16;
      *(u32x4*)(pr + jb)     = (u32x4){pr_[0],pr_[1],pr_[2],pr_[3]};
      *(u32x4*)(pr + jb + 8) = (u32x4){pr_[4],pr_[5],pr_[6],pr_[7]};
      *(u32x4*)(pi + jb)     = (u32x4){pi_[0],pi_[1],pi_[2],pi_[3]};
      *(u32x4*)(pi + jb + 8) = (u32x4){pi_[4],pi_[5],pi_[6],pi_[7]};
    }
  }
}

// ---------- transpose yT[h][r][l] -> ybuf[m][h] (bf16, full) ----------
__global__ void k_yT(const unsigned short* yT, unsigned short* ybuf){
  __shared__ unsigned short t[64][72];
  int blk = blockIdx.x;
  int h0 = (blk & 7) << 6;
  int l0 = ((blk >> 3) & 3) << 6;
  int rg = blk >> 5;                     // 0..255
  int tt = threadIdx.x;
  #pragma unroll
  for (int p = 0; p < 2; ++p){
    int e = p*2048 + tt*8;
    int row = e >> 6, col = e & 63;
    *(uint4*)&t[row][col] = *(const uint4*)(yT + ((size_t)(h0+row)*RF + rg)*256 + l0 + col);
  }
  __syncthreads();
  #pragma unroll
  for (int p = 0; p < 2; ++p){
    int e = p*2048 + tt*8;
    int orow = e >> 6, oc = e & 63;
    unsigned int d0 = (unsigned int)t[oc+0][orow] | ((unsigned int)t[oc+1][orow] << 16);
    unsigned int d1 = (unsigned int)t[oc+2][orow] | ((unsigned int)t[oc+3][orow] << 16);
    unsigned int d2 = (unsigned int)t[oc+4][orow] | ((unsigned int)t[oc+5][orow] << 16);
    unsigned int d3 = (unsigned int)t[oc+6][orow] | ((unsigned int)t[oc+7][orow] << 16);
    *(u32x4*)(ybuf + ((size_t)(rg*256 + l0 + orow))*DM + h0 + oc) = (u32x4){d0,d1,d2,d3};
  }
}

// ---------- pass2: fused local-state GEMM + in-block scan + Toeplitz/state GEMM ----------
__global__ __launch_bounds__(256) void k_p2(const unsigned short* xT, const unsigned short* KrevA,
      const unsigned short* KrevB, const unsigned short* V, const unsigned short* Wv,
      const float* coef, const float* Dsk, unsigned short* yT, int ly){
  __shared__ unsigned short us[64*256];
  __shared__ unsigned short st[64*64];
  int blk = blockIdx.x;
  int h  = blk >> 2;
  int r0 = (blk & 3) << 6;
  int tt = threadIdx.x;
  int lane = tt & 63, wv = tt >> 6;
  int la = lane & 15, kb = lane >> 4;
  const unsigned short* xp = xT + ((size_t)h*RF + r0)*256;
  #pragma unroll
  for (int p = 0; p < 8; ++p){
    int e = (p*256 + tt)*8;
    int r = e >> 8, j = e & 255;
    int g = ((j >> 3) ^ (r & 7));
    *(uint4*)&us[r*256 + g*8] = *(const uint4*)(xp + r*256 + j);
  }
  __syncthreads();
  {
    int wr = wv & 1, wm = wv >> 1;
    f32x4 sacc[2][2] = {};
    const unsigned short* wvp = Wv + (size_t)h*64*256;
    for (int j0 = 0; j0 < 256; j0 += 32){
      bf16x8 uf[2], wf[2];
      #pragma unroll
      for (int i = 0; i < 2; ++i){
        int r = wr*32 + i*16 + la;
        int g = (((j0 + kb*8) >> 3) ^ (r & 7));
        uf[i] = *(const bf16x8*)&us[r*256 + g*8];
      }
      #pragma unroll
      for (int i = 0; i < 2; ++i){
        int m2 = wm*32 + i*16 + la;
        wf[i] = *(const bf16x8*)(wvp + m2*256 + j0 + kb*8);
      }
      #pragma unroll
      for (int a = 0; a < 2; ++a)
        #pragma unroll
        for (int b = 0; b < 2; ++b)
          sacc[a][b] = __builtin_amdgcn_mfma_f32_16x16x32_bf16(uf[a], wf[b], sacc[a][b], 0, 0, 0);
    }
    #pragma unroll
    for (int a = 0; a < 2; ++a)
      #pragma unroll
      for (int b = 0; b < 2; ++b)
        #pragma unroll
        for (int q = 0; q < 4; ++q){
          int rl = wr*32 + a*16 + kb*4 + q;
          int m2 = wm*32 + b*16 + la;
          int slot = ((m2 >> 3) ^ (rl & 7));
          st[rl*64 + slot*8 + (m2 & 7)] = f2us(sacc[a][b][q]);
        }
  }
  __syncthreads();
  {
    int nm = lane & 31;
    float sgn = (lane < 32) ? -1.f : 1.f;
    int o = ((ly*NST + nm) << 9) + h;
    float wTre = coef[4*SZC + o], wTim = coef[5*SZC + o];
    float S = 0.f;
    int slot0 = lane >> 3, c0 = lane & 7;
    for (int c = 0; c < NCH; ++c){
      int rl = wv*16 + c;
      int idx = rl*64 + ((slot0 ^ (rl & 7)) << 3) + c0;
      float loc = us2f(st[idx]);
      st[idx] = f2us(S);
      float prt = __shfl_xor(S, 32);
      S = fmaf(wTre, S, fmaf(sgn*wTim, prt, loc));
    }
  }
  __syncthreads();
  int wl = wv >> 1, wr = wv & 1;
  const unsigned short* KA = KrevA + (size_t)h*KREVN;
  const unsigned short* KB = KrevB + (size_t)h*KREVN;
  const unsigned short* Vp = V + (size_t)h*256*64;
  float Dv = Dsk[ly*DM + h];
  unsigned short* yp = yT + (size_t)h*RF*256;
  for (int lt = 0; lt < 4; ++lt){
    int l0w = lt*64 + wl*32;
    f32x4 acc[2][2] = {};
    int jsteps = (l0w >> 5) + 1;
    for (int js = 0; js < jsteps; ++js){
      int j0 = js*32;
      bf16x8 uf[2], tf[2];
      #pragma unroll
      for (int i = 0; i < 2; ++i){
        int rb = wr*32 + i*16 + la;
        int g = (((j0 + kb*8) >> 3) ^ (rb & 7));
        uf[i] = *(const bf16x8*)&us[rb*256 + g*8];
      }
      #pragma unroll
      for (int i = 0; i < 2; ++i){
        int l = l0w + i*16 + la;
        int idx = 255 - l + j0 + kb*8;
        const unsigned short* base = (idx & 1) ? (KB + idx - 1) : (KA + idx);
        unsigned int d0 = *(const unsigned int*)(base);
        unsigned int d1 = *(const unsigned int*)(base + 2);
        unsigned int d2 = *(const unsigned int*)(base + 4);
        unsigned int d3 = *(const unsigned int*)(base + 6);
        tf[i] = __builtin_bit_cast(bf16x8, (u32x4){d0,d1,d2,d3});
      }
      #pragma unroll
      for (int a = 0; a < 2; ++a)
        #pragma unroll
        for (int b = 0; b < 2; ++b)
          acc[a][b] = __builtin_amdgcn_mfma_f32_16x16x32_bf16(uf[a], tf[b], acc[a][b], 0, 0, 0);
    }
    #pragma unroll
    for (int ms = 0; ms < 2; ++ms){
      int m0 = ms*32;
      bf16x8 sf[2], vf[2];
      #pragma unroll
      for (int i = 0; i < 2; ++i){
        int rb = wr*32 + i*16 + la;
        int slot = ((m0 + kb*8) >> 3) ^ (rb & 7);
        sf[i] = *(const bf16x8*)&st[rb*64 + slot*8];
      }
      #pragma unroll
      for (int i = 0; i < 2; ++i){
        int l = l0w + i*16 + la;
        vf[i] = *(const bf16x8*)(Vp + l*64 + m0 + kb*8);
      }
      #pragma unroll
      for (int a = 0; a < 2; ++a)
        #pragma unroll
        for (int b = 0; b < 2; ++b)
          acc[a][b] = __builtin_amdgcn_mfma_f32_16x16x32_bf16(sf[a], vf[b], acc[a][b], 0, 0, 0);
    }
    #pragma unroll
    for (int a = 0; a < 2; ++a)
      #pragma unroll
      for (int b = 0; b < 2; ++b)
        #pragma unroll
        for (int q = 0; q < 4; ++q){
          int rb = wr*32 + a*16 + kb*4 + q;
          int l  = l0w + b*16 + la;
          int g = ((l >> 3) ^ (rb & 7));
          float u = us2f(us[rb*256 + g*8 + (l & 7)]);
          float y = acc[a][b][q] + Dv*u;
          float gl = 0.5f*y*(1.0f + erff(y*0.70710678118654752f));
          yp[(r0 + rb)*256 + l] = f2us(gl);
        }
  }
}

// ---------- GLU GEMM: reg-staged BK=64 (0 bank conflicts) + XCD swizzle ----------
__global__ __launch_bounds__(256,2) void k_gemm(const unsigned short* A, const unsigned short* Bw,
                                                const float* bias, unsigned short* x, int ly){
  __shared__ short As[128*64];
  __shared__ short Bs[2][128*64];
  const int K = 512;
  int bid = blockIdx.x;
  int swz = (bid & 7) * 256 + (bid >> 3);     // XCD-aware bijective swizzle (2048 = 8*256)
  int Mt = swz >> 2;
  int Nt = swz & 3;
  int lane = threadIdx.x & 63, wv = threadIdx.x >> 6;
  int wm = wv >> 1, wn = wv & 1;
  f32x4 acc[2][4][4] = {};
  const unsigned short* Ag = A  + (size_t)Mt * 128 * K;
  const unsigned short* B0 = Bw + (size_t)ly * 1024 * K + (size_t)Nt * 128 * K;
  const unsigned short* B1 = B0 + (size_t)512 * K;
  for (int k0 = 0; k0 < K; k0 += 64){
    __syncthreads();
    #pragma unroll
    for (int p = 0; p < 4; ++p){
      int e = (p*256 + threadIdx.x) * 8;
      int row = e >> 6, k = e & 63;
      int sw = ((k >> 3) ^ (row & 7)) << 3;
      *(uint4*)(&As[row*64 + sw])    = *(const uint4*)(Ag + (size_t)row*K + k0 + k);
      *(uint4*)(&Bs[0][row*64 + sw]) = *(const uint4*)(B0 + (size_t)row*K + k0 + k);
      *(uint4*)(&Bs[1][row*64 + sw]) = *(const uint4*)(B1 + (size_t)row*K + k0 + k);
    }
    __syncthreads();
    #pragma unroll
    for (int kk = 0; kk < 64; kk += 32){
      int kb = (kk >> 3) + (lane >> 4);
      bf16x8 af[4], b0[4], b1[4];
      #pragma unroll
      for (int i = 0; i < 4; ++i){
        int ra = wm*64 + i*16 + (lane & 15);
        af[i] = *(const bf16x8*)(&As[ra*64 + ((kb ^ (ra & 7)) << 3)]);
        int rb = wn*64 + i*16 + (lane & 15);
        b0[i] = *(const bf16x8*)(&Bs[0][rb*64 + ((kb ^ (rb & 7)) << 3)]);
        b1[i] = *(const bf16x8*)(&Bs[1][rb*64 + ((kb ^ (rb & 7)) << 3)]);
      }
      #pragma unroll
      for (int i = 0; i < 4; ++i)
        #pragma unroll
        for (int j = 0; j < 4; ++j){
          acc[0][i][j] = __builtin_amdgcn_mfma_f32_16x16x32_bf16(af[i], b0[j], acc[0][i][j], 0, 0, 0);
          acc[1][i][j] = __builtin_amdgcn_mfma_f32_16x16x32_bf16(af[i], b1[j], acc[1][i][j], 0, 0, 0);
        }
    }
  }
  #pragma unroll
  for (int j = 0; j < 4; ++j){
    int n = Nt*128 + wn*64 + j*16 + (lane & 15);
    float ba = bias[ly*1024 + n];
    float bg = bias[ly*1024 + 512 + n];
    #pragma unroll
    for (int i = 0; i < 4; ++i){
      int mb = Mt*128 + wm*64 + i*16 + ((lane >> 4) << 2);
      #pragma unroll
      for (int q = 0; q < 4; ++q){
        float a = acc[0][i][j][q] + ba;
        float g = acc[1][i][j][q] + bg;
        float glu = a / (1.0f + expf(-g));
        size_t off = (size_t)(mb + q) * DM + n;
        x[off] = f2us(us2f(x[off]) + glu);
      }
    }
  }
}

// ---------- fused LayerNorm + transpose (layers 0..NL-2) ----------
__global__ __launch_bounds__(256) void k_lnxT(unsigned short* x, const float* gam,
                                              const float* bet, unsigned short* xT, int ly){
  __shared__ unsigned short t[64*512];
  int blk = blockIdx.x;                 // 1024 blocks
  int rr = blk >> 2;
  int j0 = (blk & 3) << 6;
  int tt = threadIdx.x;
  int lane = tt & 63, wv = tt >> 6;
  const float* gp  = gam + ly*DM + lane*8;
  const float* bp2 = bet + ly*DM + lane*8;
  float4 g0 = *(const float4*)gp,  g1 = *(const float4*)(gp + 4);
  float4 b0 = *(const float4*)bp2, b1 = *(const float4*)(bp2 + 4);
  for (int rw = 0; rw < 16; ++rw){
    int jl = wv*16 + rw;
    size_t m = (size_t)blk*64 + jl;
    unsigned short* xr = x + m*DM + lane*8;
    ushort4 a0 = *(const ushort4*)xr;
    ushort4 a1 = *(const ushort4*)(xr + 4);
    float v[8];
    v[0]=us2f(a0.x); v[1]=us2f(a0.y); v[2]=us2f(a0.z); v[3]=us2f(a0.w);
    v[4]=us2f(a1.x); v[5]=us2f(a1.y); v[6]=us2f(a1.z); v[7]=us2f(a1.w);
    float s = 0.f, s2 = 0.f;
    #pragma unroll
    for (int i = 0; i < 8; ++i){ s += v[i]; s2 += v[i]*v[i]; }
    #pragma unroll
    for (int mm = 32; mm > 0; mm >>= 1){
      s  += __shfl_xor(s,  mm, 64);
      s2 += __shfl_xor(s2, mm, 64);
    }
    float mu  = s * (1.0f/DM);
    float var = s2 * (1.0f/DM) - mu*mu;
    float rs  = rsqrtf(var + 1e-5f);
    ushort4 o0, o1;
    o0.x = f2us((v[0]-mu)*rs*g0.x + b0.x);
    o0.y = f2us((v[1]-mu)*rs*g0.y + b0.y);
    o0.z = f2us((v[2]-mu)*rs*g0.z + b0.z);
    o0.w = f2us((v[3]-mu)*rs*g0.w + b0.w);
    o1.x = f2us((v[4]-mu)*rs*g1.x + b1.x);
    o1.y = f2us((v[5]-mu)*rs*g1.y + b1.y);
    o1.z = f2us((v[6]-mu)*rs*g1.z + b1.z);
    o1.w = f2us((v[7]-mu)*rs*g1.w + b1.w);
    *(ushort4*)xr       = o0;
    *(ushort4*)(xr + 4) = o1;
    int slot = lane ^ ((jl >> 3) & 7);
    *(ushort4*)&t[jl*512 + slot*8]     = o0;
    *(ushort4*)&t[jl*512 + slot*8 + 4] = o1;
  }
  __syncthreads();
  #pragma unroll
  for (int p = 0; p < 16; ++p){
    int s = p*256 + tt;
    int h = s >> 3;
    int jg = (s & 7) << 3;
    int gh = h >> 3, h0 = h & 7;
    int slot = gh ^ (jg >> 3);
    unsigned int e0 = t[(jg+0)*512 + slot*8 + h0];
    unsigned int e1 = t[(jg+1)*512 + slot*8 + h0];
    unsigned int e2 = t[(jg+2)*512 + slot*8 + h0];
    unsigned int e3 = t[(jg+3)*512 + slot*8 + h0];
    unsigned int e4 = t[(jg+4)*512 + slot*8 + h0];
    unsigned int e5 = t[(jg+5)*512 + slot*8 + h0];
    unsigned int e6 = t[(jg+6)*512 + slot*8 + h0];
    unsigned int e7 = t[(jg+7)*512 + slot*8 + h0];
    u32x4 d;
    d.x = e0 | (e1 << 16);
    d.y = e2 | (e3 << 16);
    d.z = e4 | (e5 << 16);
    d.w = e6 | (e7 << 16);
    *(u32x4*)(xT + ((size_t)h*RF + rr)*256 + j0 + jg) = d;
  }
}

// ---------- final layer: fused LayerNorm + output projection (fp32 out) ----------
__global__ __launch_bounds__(256) void k_lnout(const unsigned short* x, const float* gam,
                                               const float* bet, const float* Wpx,
                                               const float* bpx, float* out, int ly){
  int blk = blockIdx.x;                 // 1024 blocks, 64 rows each
  int tt = threadIdx.x;
  int lane = tt & 63, wv = tt >> 6;
  const float* gp  = gam + ly*DM + lane*8;
  const float* bp2 = bet + ly*DM + lane*8;
  float4 g0 = *(const float4*)gp,  g1 = *(const float4*)(gp + 4);
  float4 b0 = *(const float4*)bp2, b1 = *(const float4*)(bp2 + 4);
  for (int rw = 0; rw < 16; ++rw){
    int jl = wv*16 + rw;
    size_t m = (size_t)blk*64 + jl;
    const unsigned short* xr = x + m*DM + lane*8;
    ushort4 a0 = *(const ushort4*)xr;
    ushort4 a1 = *(const ushort4*)(xr + 4);
    float v[8];
    v[0]=us2f(a0.x); v[1]=us2f(a0.y); v[2]=us2f(a0.z); v[3]=us2f(a0.w);
    v[4]=us2f(a1.x); v[5]=us2f(a1.y); v[6]=us2f(a1.z); v[7]=us2f(a1.w);
    float s = 0.f, s2 = 0.f;
    #pragma unroll
    for (int i = 0; i < 8; ++i){ s += v[i]; s2 += v[i]*v[i]; }
    #pragma unroll
    for (int mm = 32; mm > 0; mm >>= 1){
      s  += __shfl_xor(s,  mm, 64);
      s2 += __shfl_xor(s2, mm, 64);
    }
    float mu  = s * (1.0f/DM);
    float var = s2 * (1.0f/DM) - mu*mu;
    float rs  = rsqrtf(var + 1e-5f);
    float vv[8];
    vv[0] = us2f(f2us((v[0]-mu)*rs*g0.x + b0.x));
    vv[1] = us2f(f2us((v[1]-mu)*rs*g0.y + b0.y));
    vv[2] = us2f(f2us((v[2]-mu)*rs*g0.z + b0.z));
    vv[3] = us2f(f2us((v[3]-mu)*rs*g0.w + b0.w));
    vv[4] = us2f(f2us((v[4]-mu)*rs*g1.x + b1.x));
    vv[5] = us2f(f2us((v[5]-mu)*rs*g1.y + b1.y));
    vv[6] = us2f(f2us((v[6]-mu)*rs*g1.z + b1.z));
    vv[7] = us2f(f2us((v[7]-mu)*rs*g1.w + b1.w));
    float p[6];
    #pragma unroll
    for (int c = 0; c < 6; ++c){
      const float* wr = Wpx + c*DM + lane*8;
      float4 w0 = *(const float4*)wr, w1 = *(const float4*)(wr + 4);
      float ss = vv[0]*w0.x + vv[1]*w0.y + vv[2]*w0.z + vv[3]*w0.w
               + vv[4]*w1.x + vv[5]*w1.y + vv[6]*w1.z + vv[7]*w1.w;
      #pragma unroll
      for (int mm = 32; mm > 0; mm >>= 1) ss += __shfl_xor(ss, mm, 64);
      p[c] = ss;
    }
    if (lane == 0){
      int b = (int)(m >> 12), l = (int)(m & 4095);
      #pragma unroll
      for (int c = 0; c < 3; ++c)
        out[((b*3 + c) << 12) + l] = p[c] + bpx[c];
      #pragma unroll
      for (int c = 3; c < 6; ++c)
        out[B_*3*LSEQ + ((b*3 + (c-3)) << 12) + l] = p[c] + bpx[c];
    }
  }
}

// ---------- launcher ----------
extern "C" void kernel_launch(void* const* d_in, const int* in_sizes, int n_in,
                              void* d_out, int out_size, void* d_ws, size_t ws_size,
                              hipStream_t stream) {
  const float* z     = (const float*)d_in[0];
  const float* Wp    = (const float*)d_in[1];
  const float* bp    = (const float*)d_in[2];
  const float* pos   = (const float*)d_in[3];
  const float* logdt = (const float*)d_in[4];
  const float* Cre   = (const float*)d_in[5];
  const float* Cim   = (const float*)d_in[6];
  const float* lAr   = (const float*)d_in[7];
  const float* Aimg  = (const float*)d_in[8];
  const float* Dsk   = (const float*)d_in[9];
  const float* Wc    = (const float*)d_in[10];
  const float* bc    = (const float*)d_in[11];
  const float* lng   = (const float*)d_in[12];
  const float* lnb   = (const float*)d_in[13];
  const float* Wpx   = (const float*)d_in[14];
  const float* bpx   = (const float*)d_in[15];
  float* out = (float*)d_out;

  char* ws = (char*)d_ws;
  unsigned short* x     = (unsigned short*)(ws);                 //  67,108,864
  unsigned short* xT    = (unsigned short*)(ws + 67108864);      //  67,108,864 (slotA: xT / ybuf)
  unsigned short* yT    = (unsigned short*)(ws + 134217728);     //  67,108,864 (slotB)
  unsigned short* ybuf  = xT;                                    //  alias: xT dead after k_p2
  unsigned short* V     = (unsigned short*)(ws + 218103808);     //  16,777,216
  unsigned short* Wv    = (unsigned short*)(ws + 234881024);     //  16,777,216
  unsigned short* KrevA = (unsigned short*)(ws + 251658240);     //     557,056
  unsigned short* KrevB = (unsigned short*)(ws + 252215296);     //     557,056
  float*          cf    = (float*)(ws + 252772352);              //   1,572,864
  unsigned short* Wcb   = (unsigned short*)(ws + 254345216);     //   4,194,304
  float*          pz    = (float*)(ws + 258539520);              //      32,768
  // total = 258,572,288 bytes

  k_pre   <<<1584, 256, 0, stream>>>(logdt, Cre, Cim, lAr, Aimg, cf,
                                     Wc, Wcb, z, Wp, bp, pz, (u32x4*)KrevA);
  k_bcastT<<<1024, 256, 0, stream>>>(pz, pos, x, xT);
  for (int ly = 0; ly < NL; ++ly){
    k_kvw <<<1088, 256, 0, stream>>>(logdt, lAr, Aimg, cf, KrevA, KrevB, V, Wv, ly);
    k_p2  <<<2048, 256, 0, stream>>>(xT, KrevA, KrevB, V, Wv, cf, Dsk, yT, ly);
    k_yT  <<<8192, 256, 0, stream>>>(yT, ybuf);
    k_gemm<<<2048, 256, 0, stream>>>(ybuf, Wcb, bc, x, ly);
    if (ly < NL-1) k_lnxT <<<1024, 256, 0, stream>>>(x, lng, lnb, xT, ly);
    else           k_lnout<<<1024, 256, 0, stream>>>(x, lng, lnb, Wpx, bpx, out, ly);
  }
}